// Round 6
// baseline (1145.287 us; speedup 1.0000x reference)
//
#include <hip/hip_runtime.h>

typedef unsigned short u16;
typedef unsigned char u8;
typedef __attribute__((ext_vector_type(4))) float f32x4;
typedef __attribute__((ext_vector_type(8))) short bf16x8;

#define BL 2048   // B*L

__device__ __forceinline__ u16 f2bf(float f) {
  unsigned u = __float_as_uint(f);
  u += 0x7fffu + ((u >> 16) & 1u);
  return (u16)(u >> 16);
}
__device__ __forceinline__ float bf2f(u16 x) {
  return __uint_as_float(((unsigned)x) << 16);
}
// float -> OCP e4m3fn (RNE, saturate to 448) — software path (prep/init only)
__device__ __forceinline__ u8 f2e4m3(float f) {
  unsigned u = __float_as_uint(f);
  unsigned s = (u >> 24) & 0x80u;
  float a = fabsf(f);
  a = fminf(a, 448.f);
  if (a < 0.015625f) {
    int m = (int)(a * 512.f + 0.5f);
    return (u8)(s | (unsigned)m);
  }
  unsigned au = __float_as_uint(a);
  au += 0x7ffffu + ((au >> 20) & 1u);
  unsigned e = (au >> 23) - 127u + 7u;
  unsigned m = (au >> 20) & 7u;
  return (u8)(s | (e << 3) | m);
}
__device__ __forceinline__ float sigm(float x) {
  float e = __expf(-fabsf(x));
  float s = 1.f / (1.f + e);
  return x >= 0.f ? s : 1.f - s;
}
__device__ __forceinline__ float tanh_s(float x) {
  float e = __expf(-2.f * fabsf(x));
  float t = (1.f - e) / (1.f + e);
  return x >= 0.f ? t : -t;
}

// ---------------- prep: weight conversions + fused biases + zero scalars ----------------
__global__ void prep_kernel(const float* __restrict__ wih0, const float* __restrict__ wih1,
                            const float* __restrict__ whp, const float* __restrict__ wu,
                            const float* __restrict__ wv, const float* __restrict__ wuv,
                            const float* __restrict__ bu, const float* __restrict__ bv,
                            const float* __restrict__ whh0, const float* __restrict__ whh1,
                            const float* __restrict__ bih0, const float* __restrict__ bhh0,
                            const float* __restrict__ bih1, const float* __restrict__ bhh1,
                            u16* __restrict__ o_wih0, u16* __restrict__ o_wih1,
                            u16* __restrict__ o_whp, u16* __restrict__ o_wuvpad,
                            u16* __restrict__ o_wuvc, float* __restrict__ o_buv2,
                            float* __restrict__ scal, u8* __restrict__ o_wf8,
                            float* __restrict__ o_bc, float* __restrict__ o_bhhn) {
  long i = (long)blockIdx.x * 256 + threadIdx.x;
  const long c1 = 393216, c2 = 1179648, c3 = 1310720, c4 = 1458176,
             c5 = 1490944, c6 = 1491200, c7 = 1491216,
             c8 = 2277648, c9 = 2280720, c10 = 2281744;
  if (i < c1) { o_wih0[i] = f2bf(wih0[i]); return; }
  if (i < c2) { long j = i - c1; o_wih1[j] = f2bf(wih1[j]); return; }
  if (i < c3) { long j = i - c2; o_whp[j] = f2bf(whp[j]); return; }
  if (i < c4) {
    long j = i - c3; int n = (int)(j / 576), k = (int)(j % 576);
    float v = 0.f;
    if (k < 545) v = (n < 128) ? wu[n * 545 + k] : wv[(n - 128) * 545 + k];
    o_wuvpad[j] = f2bf(v); return;
  }
  if (i < c5) {
    long j = i - c4; int n = (int)(j / 128), k = (int)(j % 128);
    float v = (n < 128) ? wuv[n * 256 + k] : wuv[(n - 128) * 256 + 128 + k];
    o_wuvc[j] = f2bf(v); return;
  }
  if (i < c6) { int n = (int)(i - c5); o_buv2[n] = (n < 128) ? bu[n] : bv[n - 128]; return; }
  if (i < c7) { scal[i - c6] = 0.f; return; }
  if (i < c8) {  // wf8[2 layers][2 dirs][768][256] e4m3
    long j = i - c7;
    int layer = (int)(j / 393216);
    long r = j % 393216;
    float v = layer ? whh1[r] : whh0[r];
    o_wf8[j] = f2e4m3(v); return;
  }
  if (i < c9) {  // bc[2 layers][2 dirs][768]: bih + (g<2 ? bhh : 0)
    long j = i - c8;
    int layer = (int)(j / 1536);
    int k2 = (int)(j % 1536);
    float v = (layer ? bih1[k2] : bih0[k2]);
    if ((k2 % 768) < 512) v += (layer ? bhh1[k2] : bhh0[k2]);
    o_bc[j] = v; return;
  }
  if (i < c10) {  // bhhn[2 layers][2 dirs][256] = bhh n-gate part
    long j = i - c9;
    int layer = (int)(j / 512);
    int k3 = (int)(j % 512);
    int idx = (k3 / 256) * 768 + 512 + (k3 % 256);
    o_bhhn[j] = layer ? bhh1[idx] : bhh0[idx];
    return;
  }
}

// ---------------- embedding gather -> bf16 ----------------
__global__ void gather_x(const int* __restrict__ text, const float* __restrict__ embw,
                         u16* __restrict__ xbf) {
  int i = blockIdx.x * 256 + threadIdx.x;
  if (i >= BL * 256) return;
  int bl = i >> 8, k = i & 255;
  xbf[i] = f2bf(embw[(long)text[bl] * 256 + k]);
}

// ---------------- generic bf16 MFMA GEMM: C[M,N] = A[M,K] @ B[N,K]^T + bias ----------------
// gimode=1: remap output (m,n) -> [t][dir][768][16] (batch innermost) for GRU gate loads
__global__ __launch_bounds__(256) void gemm_bf16(
    const u16* __restrict__ A, int lda, const u16* __restrict__ Bm,
    const float* __restrict__ bias, float* __restrict__ C, u16* __restrict__ Cbf,
    int ldc, int M, int N, int K, int gimode) {
  __shared__ u16 As[64 * 40];
  __shared__ u16 Bs[64 * 40];
  const int tid = threadIdx.x;
  const int w = tid >> 6, l = tid & 63, c = l & 15, q = l >> 4;
  const int m0 = blockIdx.x * 64, n0 = blockIdx.y * 64;
  const int srow = tid >> 2, sq = tid & 3;
  f32x4 zero = {0.f, 0.f, 0.f, 0.f};
  f32x4 acc[4] = {zero, zero, zero, zero};
  for (int k0 = 0; k0 < K; k0 += 32) {
    *(bf16x8*)(As + srow * 40 + sq * 8) =
        *(const bf16x8*)(A + (long)(m0 + srow) * lda + k0 + sq * 8);
    *(bf16x8*)(Bs + srow * 40 + sq * 8) =
        *(const bf16x8*)(Bm + (long)(n0 + srow) * K + k0 + sq * 8);
    __syncthreads();
    bf16x8 a = *(const bf16x8*)(As + (w * 16 + c) * 40 + q * 8);
#pragma unroll
    for (int nt = 0; nt < 4; ++nt) {
      bf16x8 b = *(const bf16x8*)(Bs + (nt * 16 + c) * 40 + q * 8);
      acc[nt] = __builtin_amdgcn_mfma_f32_16x16x32_bf16(a, b, acc[nt], 0, 0, 0);
    }
    __syncthreads();
  }
#pragma unroll
  for (int nt = 0; nt < 4; ++nt) {
    int n = n0 + nt * 16 + c;
    float bv = bias ? bias[n] : 0.f;
#pragma unroll
    for (int r = 0; r < 4; ++r) {
      int m = m0 + w * 16 + q * 4 + r;
      float v = acc[nt][r] + bv;
      long off;
      if (gimode) {
        int t = m & 127, b = m >> 7;
        int dir = (n >= 768) ? 1 : 0;
        int rest = n - dir * 768;
        off = ((long)(t * 2 + dir) * 768 + rest) * 16 + b;
      } else {
        off = (long)m * ldc + n;
      }
      if (C) C[off] = v;
      if (Cbf) Cbf[off] = f2bf(v);
    }
  }
}

// ---------------- GRU scan: fp8 recurrent weights fully register-resident ----------------
// 1024 threads = 16 waves; wave w owns hidden slice hd = w*16..w*16+15 and its three
// gate tiles (N = hd, 256+hd, 512+hd) -> per-thread Breg = 24 longs = 48 VGPRs.
// Whole 192KB w_hh lives in the block's register file; h state in 4KB LDS.
// gi2 layout: [128][2][768][16] f32 (r/z include b_ih+b_hh; n includes b_ih only)
__global__ __launch_bounds__(1024) void gru_scan(
    const float* __restrict__ gi2,
    const u8* __restrict__ wf8l,
    const float* __restrict__ bhhn_l,
    const float* __restrict__ h0,       // [4][16][256]
    int layer, float* __restrict__ hn,  // [4][16][256]
    u16* __restrict__ ybf)              // [BL][512] bf16
{
  __shared__ u8 hq[16 * 264];  // h state e4m3, stride 264 (8-aligned)
  const int dir = blockIdx.x;
  const int tid = threadIdx.x;
  const int w = tid >> 6, l = tid & 63, c = l & 15, q = l >> 4;
  const u8* wdir = wf8l + (long)dir * 768 * 256;
  const int hd = w * 16 + c;  // hidden column 0..255

  // B fragments: Breg[kt][g] covers gate tile g at k-slice kt
  long Breg[8][3];
#pragma unroll
  for (int kt = 0; kt < 8; ++kt)
#pragma unroll
    for (int g = 0; g < 3; ++g)
      Breg[kt][g] = *(const long*)(wdir + (long)(g * 256 + hd) * 256 + kt * 32 + q * 8);
  const float bias_n = bhhn_l[dir * 256 + hd];

  float hprev[4];
  const int hbase = (layer * 2 + dir) * (16 * 256);
#pragma unroll
  for (int r = 0; r < 4; ++r) {
    int m = q * 4 + r;
    float v = h0[hbase + m * 256 + hd];
    hprev[r] = v;
    hq[m * 264 + hd] = f2e4m3(v);
  }

  const int tt0 = dir ? 127 : 0;
  const long gstep = dir ? -(long)(2 * 768 * 16) : (long)(2 * 768 * 16);
  const long ystep = dir ? -512 : 512;
  const float* gp = gi2 + ((long)(tt0 * 2 + dir) * 768 + hd) * 16 + q * 4;
  u16* yp = ybf + ((long)(q * 4 * 128 + tt0)) * 512 + dir * 256 + hd;

  // pre-load step-0 gates
  f32x4 curg[3];
#pragma unroll
  for (int g = 0; g < 3; ++g) curg[g] = *(const f32x4*)(gp + g * 256 * 16);
  __syncthreads();

#pragma unroll 1
  for (int t = 0; t < 128; ++t) {
    f32x4 acc[3];
    acc[0] = curg[0];
    acc[1] = curg[1];
    f32x4 bn = {bias_n, bias_n, bias_n, bias_n};
    acc[2] = bn;
    // prefetch next step's gates during MFMA section (hides HBM latency)
    const float* gpn = gp + gstep;
    f32x4 nxt0 = acc[0], nxt1 = acc[1], nxt2 = curg[2];
    if (t < 127) {
      nxt0 = *(const f32x4*)(gpn + 0);
      nxt1 = *(const f32x4*)(gpn + 256 * 16);
      nxt2 = *(const f32x4*)(gpn + 512 * 16);
    }
#pragma unroll
    for (int kt = 0; kt < 8; ++kt) {
      long a = *(const long*)(hq + c * 264 + kt * 32 + q * 8);
#pragma unroll
      for (int g = 0; g < 3; ++g)
        acc[g] = __builtin_amdgcn_mfma_f32_16x16x32_fp8_fp8(a, Breg[kt][g], acc[g], 0, 0, 0);
    }
    __syncthreads();  // all hq reads done before epilogue writes
    float hv4[4];
#pragma unroll
    for (int r = 0; r < 4; ++r) {
      float rg = sigm(acc[0][r]);
      float zg = sigm(acc[1][r]);
      float ng = tanh_s(curg[2][r] + rg * acc[2][r]);
      float hv = (1.f - zg) * ng + zg * hprev[r];
      hprev[r] = hv;
      hv4[r] = hv;
      yp[r * 65536] = f2bf(hv);
    }
    // HW packed fp8 convert: 2 values per instruction
    int pk01 = __builtin_amdgcn_cvt_pk_fp8_f32(hv4[0], hv4[1], 0, false);
    int pk23 = __builtin_amdgcn_cvt_pk_fp8_f32(hv4[2], hv4[3], 0, false);
    hq[(q * 4 + 0) * 264 + hd] = (u8)(pk01 & 0xff);
    hq[(q * 4 + 1) * 264 + hd] = (u8)((pk01 >> 8) & 0xff);
    hq[(q * 4 + 2) * 264 + hd] = (u8)(pk23 & 0xff);
    hq[(q * 4 + 3) * 264 + hd] = (u8)((pk23 >> 8) & 0xff);
    curg[0] = nxt0; curg[1] = nxt1; curg[2] = nxt2;
    gp = gpn;
    yp += ystep;
    __syncthreads();  // hq writes visible before next step's reads
  }
#pragma unroll
  for (int r = 0; r < 4; ++r)
    hn[hbase + (q * 4 + r) * 256 + hd] = hprev[r];
}

// ---------------- attention softmax ----------------
__global__ void attn_kernel(const float* __restrict__ hn, const float* __restrict__ wlp,
                            const float* __restrict__ blp, const float* __restrict__ outsq,
                            float* __restrict__ attw) {
  int b = blockIdx.x, tid = threadIdx.x;
  __shared__ float hsq[256];
  __shared__ float sc[128];
  __shared__ float red[2];
  {
    float s = blp[0];
#pragma unroll
    for (int d = 0; d < 4; ++d) s += hn[d * 4096 + b * 256 + tid] * wlp[d];
    hsq[tid] = s;
  }
  __syncthreads();
  if (tid < 128) {
    float s = 0.f;
    const float* op = outsq + (long)(b * 128 + tid) * 256;
    for (int h = 0; h < 256; ++h) s += hsq[h] * op[h];
    sc[tid] = s;
  }
  __syncthreads();
  if (tid == 0) {
    float m = sc[0];
    for (int i = 1; i < 128; ++i) m = fmaxf(m, sc[i]);
    red[0] = m;
  }
  __syncthreads();
  if (tid < 128) sc[tid] = __expf(sc[tid] - red[0]);
  __syncthreads();
  if (tid == 0) {
    float s = 0.f;
    for (int i = 0; i < 128; ++i) s += sc[i];
    red[1] = s;
  }
  __syncthreads();
  if (tid < 128) attw[b * 128 + tid] = sc[tid] / red[1];
}

// ---------------- build rel_in (bf16, K padded to 576) ----------------
__global__ void build_relin(const u16* __restrict__ outbf, const int* __restrict__ tags,
                            const float* __restrict__ emb_tok, const float* __restrict__ attw,
                            u16* __restrict__ relin) {
  int i = blockIdx.x * 256 + threadIdx.x;
  if (i >= BL * 576) return;
  int bl = i / 576, cc = i % 576;
  u16 v;
  if (cc < 512) v = outbf[(long)bl * 512 + cc];
  else if (cc < 544) v = f2bf(emb_tok[tags[bl] * 32 + (cc - 512)]);
  else if (cc == 544) v = f2bf(attw[bl]);
  else v = 0;
  relin[i] = v;
}

// ---------------- ner scores [BL][10] ----------------
__global__ __launch_bounds__(256) void ner_kernel(
    const u16* __restrict__ outbf, const float* __restrict__ attw,
    const float* __restrict__ wner, const float* __restrict__ bner,
    float* __restrict__ ner) {
  __shared__ float wn[10 * 513];
  int tid = threadIdx.x;
  for (int e = tid; e < 5130; e += 256) wn[e] = wner[e];
  __syncthreads();
  int row0 = blockIdx.x * 64;
  for (int o = tid; o < 640; o += 256) {
    int rr = o / 10, t = o % 10;
    int row = row0 + rr;
    const u16* op = outbf + (long)row * 512;
    const float* wp = wn + t * 513;
    float s = bner[t] + attw[row] * wp[512];
    for (int k = 0; k < 512; ++k) s += bf2f(op[k]) * wp[k];
    ner[(long)row * 10 + t] = s;
  }
}

// ---------------- fused rel-branch BCE over 32x32 pair tiles ----------------
__global__ __launch_bounds__(512) void rel_kernel(
    const float* __restrict__ AC,    // [BL][256]: cols 0:128 = A(u-part, j), 128:256 = C(v-part, i)
    const int* __restrict__ gold,    // [16][128][128]
    const float* __restrict__ mask,  // [16][128]
    const float* __restrict__ embr,  // [24][128]
    float* __restrict__ acc_out) {
  __shared__ float Au[32 * 132];
  __shared__ float Cv[32 * 132];
  __shared__ float ER[24 * 128];
  __shared__ int GT[32 * 33];
  __shared__ float Mi[32], Mj[32];
  __shared__ float redbuf[8];
  int b = blockIdx.x, it = blockIdx.y, jt = blockIdx.z;
  int i0 = it * 32, j0 = jt * 32;
  int tid = threadIdx.x;
  for (int e = tid; e < 4096; e += 512) {
    int rr = e >> 7, h = e & 127;
    Au[rr * 132 + h] = AC[(long)(b * 128 + j0 + rr) * 256 + h];
    Cv[rr * 132 + h] = AC[(long)(b * 128 + i0 + rr) * 256 + 128 + h];
  }
  for (int e = tid; e < 3072; e += 512) ER[e] = embr[e];
  for (int e = tid; e < 1024; e += 512) {
    int ii = e >> 5, jj = e & 31;
    GT[ii * 33 + jj] = gold[(long)b * 16384 + (i0 + ii) * 128 + (j0 + jj)];
  }
  if (tid < 32) Mi[tid] = mask[b * 128 + i0 + tid];
  else if (tid < 64) Mj[tid - 32] = mask[b * 128 + j0 + tid - 32];
  __syncthreads();
  float sum = 0.f;
#pragma unroll 1
  for (int k = 0; k < 2; ++k) {
    int p = tid + k * 512;
    int ii = p >> 5, jj = p & 31;
    float pm = Mi[ii] * Mj[jj];
    int g = GT[ii * 33 + jj];
    float logits[24];
#pragma unroll
    for (int r = 0; r < 24; ++r) logits[r] = 0.f;
#pragma unroll 1
    for (int hc = 0; hc < 4; ++hc) {
      float tt[32];
#pragma unroll
      for (int x4 = 0; x4 < 8; ++x4) {
        float4 a4 = *(const float4*)(Au + jj * 132 + hc * 32 + x4 * 4);
        float4 c4 = *(const float4*)(Cv + ii * 132 + hc * 32 + x4 * 4);
        tt[x4 * 4 + 0] = tanh_s(a4.x + c4.x);
        tt[x4 * 4 + 1] = tanh_s(a4.y + c4.y);
        tt[x4 * 4 + 2] = tanh_s(a4.z + c4.z);
        tt[x4 * 4 + 3] = tanh_s(a4.w + c4.w);
      }
#pragma unroll
      for (int r = 0; r < 24; ++r) {
        float s = logits[r];
#pragma unroll
        for (int x4 = 0; x4 < 8; ++x4) {
          float4 e4 = *(const float4*)(ER + r * 128 + hc * 32 + x4 * 4);
          s += tt[x4 * 4] * e4.x + tt[x4 * 4 + 1] * e4.y +
               tt[x4 * 4 + 2] * e4.z + tt[x4 * 4 + 3] * e4.w;
        }
        logits[r] = s;
      }
    }
    float lsum = 0.f;
#pragma unroll
    for (int r = 0; r < 24; ++r) {
      float x = logits[r];
      float e = __expf(-fabsf(x));
      float l1p = __logf(1.f + e);
      float lsp = fminf(x, 0.f) - l1p;   // log_sigmoid(x)
      float lsn = fminf(-x, 0.f) - l1p;  // log_sigmoid(-x)
      float wr = r ? 50.f : 1.f;
      float pw = r ? 20.f : 1.f;
      lsum -= (r == g) ? (wr * pw * lsp) : (wr * lsn);
    }
    sum += lsum * pm;
  }
  for (int off = 32; off > 0; off >>= 1) sum += __shfl_down(sum, off, 64);
  if ((tid & 63) == 0) redbuf[tid >> 6] = sum;
  __syncthreads();
  if (tid == 0) {
    float s = 0.f;
    for (int x = 0; x < 8; ++x) s += redbuf[x];
    atomicAdd(acc_out, s);
  }
}

// ---------------- CRF log-likelihood (numerator + forward algo) ----------------
__global__ __launch_bounds__(512) void crf_kernel(
    const float* __restrict__ ner, const int* __restrict__ tags,
    const float* __restrict__ mask, const float* __restrict__ cs,
    const float* __restrict__ ct, const float* __restrict__ ce,
    float* __restrict__ scal) {
  __shared__ float tr[100];
  __shared__ float alpha[2][16][12];
  __shared__ float logZ[16], sc[16];
  __shared__ float red[8];
  int tid = threadIdx.x;
  if (tid < 100) tr[tid] = ct[tid];
  __syncthreads();
  int b = tid / 10, j = tid % 10;
  if (tid < 160) alpha[0][b][j] = cs[j] + ner[(long)(b * 128) * 10 + j];
  __syncthreads();
  int cur = 0;
  for (int t = 1; t < 128; ++t) {
    if (tid < 160) {
      float m = -1e30f;
#pragma unroll
      for (int i = 0; i < 10; ++i) m = fmaxf(m, alpha[cur][b][i] + tr[i * 10 + j]);
      float s = 0.f;
#pragma unroll
      for (int i = 0; i < 10; ++i) s += __expf(alpha[cur][b][i] + tr[i * 10 + j] - m);
      float v = m + __logf(s) + ner[(long)(b * 128 + t) * 10 + j];
      float mk = mask[b * 128 + t];
      alpha[1 - cur][b][j] = (mk > 0.f) ? v : alpha[cur][b][j];
    }
    __syncthreads();
    cur ^= 1;
  }
  if (tid < 16) {
    int bb = tid;
    float m = -1e30f;
    for (int jj = 0; jj < 10; ++jj) m = fmaxf(m, alpha[cur][bb][jj] + ce[jj]);
    float s = 0.f;
    for (int jj = 0; jj < 10; ++jj) s += __expf(alpha[cur][bb][jj] + ce[jj] - m);
    logZ[bb] = m + __logf(s);
    int tprev = tags[bb * 128];
    float sco = cs[tprev] + ner[(long)(bb * 128) * 10 + tprev];
    float msum_b = mask[bb * 128];
    for (int t = 1; t < 128; ++t) {
      int tc = tags[bb * 128 + t];
      float mk = mask[bb * 128 + t];
      sco += (tr[tprev * 10 + tc] + ner[(long)(bb * 128 + t) * 10 + tc]) * mk;
      msum_b += mk;
      tprev = tc;
    }
    int send = (int)(msum_b)-1;
    int last = tags[bb * 128 + send];
    sco += ce[last];
    sc[bb] = sco - logZ[bb];
  }
  float ms = 0.f;
  for (int e = tid; e < 2048; e += 512) ms += mask[e];
  for (int off = 32; off > 0; off >>= 1) ms += __shfl_down(ms, off, 64);
  if ((tid & 63) == 0) red[tid >> 6] = ms;
  __syncthreads();
  if (tid == 0) {
    float s = 0.f;
    for (int x = 0; x < 8; ++x) s += red[x];
    scal[1] = s;
    float llh = 0.f;
    for (int bb = 0; bb < 16; ++bb) llh += sc[bb];
    scal[0] = llh;
  }
}

__global__ void finalize_kernel(const float* __restrict__ scal, float* __restrict__ out) {
  if (threadIdx.x == 0 && blockIdx.x == 0) {
    out[0] = -scal[0];
    out[1] = scal[2] / scal[1];
  }
}

// ---------------- host launch ----------------
extern "C" void kernel_launch(void* const* d_in, const int* in_sizes, int n_in,
                              void* d_out, int out_size, void* d_ws, size_t ws_size,
                              hipStream_t stream) {
  (void)in_sizes; (void)n_in; (void)out_size; (void)ws_size;
  const int*   text = (const int*)d_in[0];
  const int*   tags = (const int*)d_in[1];
  const int*   gold = (const int*)d_in[2];
  const float* mask = (const float*)d_in[3];
  const float* h0   = (const float*)d_in[4];
  const float* embw = (const float*)d_in[5];
  const float* embt = (const float*)d_in[6];
  const float* embr = (const float*)d_in[7];
  const float* wih0 = (const float*)d_in[8];
  const float* whh0 = (const float*)d_in[9];
  const float* bih0 = (const float*)d_in[10];
  const float* bhh0 = (const float*)d_in[11];
  const float* wih1 = (const float*)d_in[12];
  const float* whh1 = (const float*)d_in[13];
  const float* bih1 = (const float*)d_in[14];
  const float* bhh1 = (const float*)d_in[15];
  const float* whp  = (const float*)d_in[16];
  const float* bhp  = (const float*)d_in[17];
  const float* wlp  = (const float*)d_in[18];
  const float* blp  = (const float*)d_in[19];
  const float* wner = (const float*)d_in[20];
  const float* bner = (const float*)d_in[21];
  const float* cs   = (const float*)d_in[22];
  const float* ct   = (const float*)d_in[23];
  const float* ce   = (const float*)d_in[24];
  const float* wu   = (const float*)d_in[25];
  const float* bu   = (const float*)d_in[26];
  const float* wv   = (const float*)d_in[27];
  const float* bv   = (const float*)d_in[28];
  const float* wuv  = (const float*)d_in[29];
  const float* buv  = (const float*)d_in[30];

  char* ws = (char*)d_ws;
  float* gi     = (float*)(ws + 0);
  u16*   xbf    = (u16*)(ws + 12582912);
  u16*   y0bf   = (u16*)(ws + 13631488);
  u8*    wf8    = (u8*)(ws + 15728640);   // [2][2][768][256] e4m3 (786432 B)
  float* bc     = (float*)(ws + 16515072);  // [2][1536] fused GEMM bias
  float* bhhn   = (float*)(ws + 16527360);  // [2][512] n-gate hh bias
  u16*   outbf  = (u16*)(ws + 19922944);
  float* hn     = (float*)(ws + 22020096);
  float* outsq  = (float*)(ws + 22085632);
  float* attw   = (float*)(ws + 24182784);
  u16*   relin  = (u16*)(ws + 24190976);
  u16*   uvbf   = (u16*)(ws + 28647424);
  float* ac32   = (float*)(ws + 29696000);
  float* ner    = (float*)(ws + 31793152);
  u16*   wih0b  = (u16*)(ws + 31875072);
  u16*   wih1b  = (u16*)(ws + 32661504);
  u16*   whpb   = (u16*)(ws + 34234368);
  u16*   wuvp   = (u16*)(ws + 34496512);
  u16*   wuvc   = (u16*)(ws + 34791424);
  float* buv2   = (float*)(ws + 34856960);
  float* scal   = (float*)(ws + 34859008);

  prep_kernel<<<8913, 256, 0, stream>>>(wih0, wih1, whp, wu, wv, wuv, bu, bv,
                                        whh0, whh1, bih0, bhh0, bih1, bhh1,
                                        wih0b, wih1b, whpb, wuvp, wuvc, buv2, scal,
                                        wf8, bc, bhhn);
  gather_x<<<2048, 256, 0, stream>>>(text, embw, xbf);
  gemm_bf16<<<dim3(32, 24), 256, 0, stream>>>(xbf, 256, wih0b, bc, gi, nullptr, 1536, 2048, 1536, 256, 1);
  gru_scan<<<2, 1024, 0, stream>>>(gi, wf8, bhhn, h0, 0, hn, y0bf);
  gemm_bf16<<<dim3(32, 24), 256, 0, stream>>>(y0bf, 512, wih1b, bc + 1536, gi, nullptr, 1536, 2048, 1536, 512, 1);
  gru_scan<<<2, 1024, 0, stream>>>(gi, wf8 + 393216, bhhn + 512, h0, 1, hn, outbf);
  gemm_bf16<<<dim3(32, 4), 256, 0, stream>>>(outbf, 512, whpb, bhp, outsq, nullptr, 256, 2048, 256, 512, 0);
  attn_kernel<<<16, 256, 0, stream>>>(hn, wlp, blp, outsq, attw);
  build_relin<<<4608, 256, 0, stream>>>(outbf, tags, embt, attw, relin);
  ner_kernel<<<32, 256, 0, stream>>>(outbf, attw, wner, bner, ner);
  gemm_bf16<<<dim3(32, 4), 256, 0, stream>>>(relin, 576, wuvp, buv2, nullptr, uvbf, 256, 2048, 256, 576, 0);
  // AC = [U @ wuv_u^T | V @ wuv_v^T + b_uv]
  gemm_bf16<<<dim3(32, 2), 256, 0, stream>>>(uvbf, 256, wuvc, nullptr, ac32, nullptr, 256, 2048, 128, 128, 0);
  gemm_bf16<<<dim3(32, 2), 256, 0, stream>>>(uvbf + 128, 256, wuvc + 128 * 128, buv, ac32 + 128, nullptr, 256, 2048, 128, 128, 0);
  rel_kernel<<<dim3(16, 4, 4), 512, 0, stream>>>(ac32, gold, mask, embr, scal + 2);
  crf_kernel<<<1, 512, 0, stream>>>(ner, tags, mask, cs, ct, ce, scal);
  finalize_kernel<<<1, 64, 0, stream>>>(scal, (float*)d_out);
}

// Round 7
// 1015.325 us; speedup vs baseline: 1.1280x; 1.1280x over previous
//
#include <hip/hip_runtime.h>

typedef unsigned short u16;
typedef unsigned char u8;
typedef unsigned long long u64;
typedef __attribute__((ext_vector_type(4))) float f32x4;
typedef __attribute__((ext_vector_type(8))) short bf16x8;

#define BL 2048   // B*L

__device__ __forceinline__ u16 f2bf(float f) {
  unsigned u = __float_as_uint(f);
  u += 0x7fffu + ((u >> 16) & 1u);
  return (u16)(u >> 16);
}
__device__ __forceinline__ float bf2f(u16 x) {
  return __uint_as_float(((unsigned)x) << 16);
}
// float -> OCP e4m3fn (RNE, saturate to 448) — software path (prep/init only)
__device__ __forceinline__ u8 f2e4m3(float f) {
  unsigned u = __float_as_uint(f);
  unsigned s = (u >> 24) & 0x80u;
  float a = fabsf(f);
  a = fminf(a, 448.f);
  if (a < 0.015625f) {
    int m = (int)(a * 512.f + 0.5f);
    return (u8)(s | (unsigned)m);
  }
  unsigned au = __float_as_uint(a);
  au += 0x7ffffu + ((au >> 20) & 1u);
  unsigned e = (au >> 23) - 127u + 7u;
  unsigned m = (au >> 20) & 7u;
  return (u8)(s | (e << 3) | m);
}
__device__ __forceinline__ float sigm(float x) {
  float e = __expf(-fabsf(x));
  float s = 1.f / (1.f + e);
  return x >= 0.f ? s : 1.f - s;
}
__device__ __forceinline__ float tanh_s(float x) {
  float e = __expf(-2.f * fabsf(x));
  float t = (1.f - e) / (1.f + e);
  return x >= 0.f ? t : -t;
}

// ---------------- prep: weight conversions + fused biases + zero scalars ----------------
__global__ void prep_kernel(const float* __restrict__ wih0, const float* __restrict__ wih1,
                            const float* __restrict__ whp, const float* __restrict__ wu,
                            const float* __restrict__ wv, const float* __restrict__ wuv,
                            const float* __restrict__ bu, const float* __restrict__ bv,
                            const float* __restrict__ whh0, const float* __restrict__ whh1,
                            const float* __restrict__ bih0, const float* __restrict__ bhh0,
                            const float* __restrict__ bih1, const float* __restrict__ bhh1,
                            u16* __restrict__ o_wih0, u16* __restrict__ o_wih1,
                            u16* __restrict__ o_whp, u16* __restrict__ o_wuvpad,
                            u16* __restrict__ o_wuvc, float* __restrict__ o_buv2,
                            float* __restrict__ scal, u8* __restrict__ o_wf8,
                            float* __restrict__ o_bc, float* __restrict__ o_bhhn) {
  long i = (long)blockIdx.x * 256 + threadIdx.x;
  const long c1 = 393216, c2 = 1179648, c3 = 1310720, c4 = 1458176,
             c5 = 1490944, c6 = 1491200, c7 = 1491216,
             c8 = 2277648, c9 = 2280720, c10 = 2281744;
  if (i < c1) { o_wih0[i] = f2bf(wih0[i]); return; }
  if (i < c2) { long j = i - c1; o_wih1[j] = f2bf(wih1[j]); return; }
  if (i < c3) { long j = i - c2; o_whp[j] = f2bf(whp[j]); return; }
  if (i < c4) {
    long j = i - c3; int n = (int)(j / 576), k = (int)(j % 576);
    float v = 0.f;
    if (k < 545) v = (n < 128) ? wu[n * 545 + k] : wv[(n - 128) * 545 + k];
    o_wuvpad[j] = f2bf(v); return;
  }
  if (i < c5) {
    long j = i - c4; int n = (int)(j / 128), k = (int)(j % 128);
    float v = (n < 128) ? wuv[n * 256 + k] : wuv[(n - 128) * 256 + 128 + k];
    o_wuvc[j] = f2bf(v); return;
  }
  if (i < c6) { int n = (int)(i - c5); o_buv2[n] = (n < 128) ? bu[n] : bv[n - 128]; return; }
  if (i < c7) { scal[i - c6] = 0.f; return; }
  if (i < c8) {  // wf8[2 layers][2 dirs][768][256] e4m3
    long j = i - c7;
    int layer = (int)(j / 393216);
    long r = j % 393216;
    float v = layer ? whh1[r] : whh0[r];
    o_wf8[j] = f2e4m3(v); return;
  }
  if (i < c9) {  // bc[2 layers][2 dirs][768]: bih + (g<2 ? bhh : 0)
    long j = i - c8;
    int layer = (int)(j / 1536);
    int k2 = (int)(j % 1536);
    float v = (layer ? bih1[k2] : bih0[k2]);
    if ((k2 % 768) < 512) v += (layer ? bhh1[k2] : bhh0[k2]);
    o_bc[j] = v; return;
  }
  if (i < c10) {  // bhhn[2 layers][2 dirs][256] = bhh n-gate part
    long j = i - c9;
    int layer = (int)(j / 512);
    int k3 = (int)(j % 512);
    int idx = (k3 / 256) * 768 + 512 + (k3 % 256);
    o_bhhn[j] = layer ? bhh1[idx] : bhh0[idx];
    return;
  }
}

// ---------------- embedding gather -> bf16 ----------------
__global__ void gather_x(const int* __restrict__ text, const float* __restrict__ embw,
                         u16* __restrict__ xbf) {
  int i = blockIdx.x * 256 + threadIdx.x;
  if (i >= BL * 256) return;
  int bl = i >> 8, k = i & 255;
  xbf[i] = f2bf(embw[(long)text[bl] * 256 + k]);
}

// ---------------- generic bf16 MFMA GEMM: C[M,N] = A[M,K] @ B[N,K]^T + bias ----------------
// gimode=1: write bf16 gates in layout [t][dir][bg][768][4] (batch-group split for GRU scan)
__global__ __launch_bounds__(256) void gemm_bf16(
    const u16* __restrict__ A, int lda, const u16* __restrict__ Bm,
    const float* __restrict__ bias, float* __restrict__ C, u16* __restrict__ Cbf,
    int ldc, int M, int N, int K, int gimode) {
  __shared__ u16 As[64 * 40];
  __shared__ u16 Bs[64 * 40];
  const int tid = threadIdx.x;
  const int w = tid >> 6, l = tid & 63, c = l & 15, q = l >> 4;
  const int m0 = blockIdx.x * 64, n0 = blockIdx.y * 64;
  const int srow = tid >> 2, sq = tid & 3;
  f32x4 zero = {0.f, 0.f, 0.f, 0.f};
  f32x4 acc[4] = {zero, zero, zero, zero};
  for (int k0 = 0; k0 < K; k0 += 32) {
    *(bf16x8*)(As + srow * 40 + sq * 8) =
        *(const bf16x8*)(A + (long)(m0 + srow) * lda + k0 + sq * 8);
    *(bf16x8*)(Bs + srow * 40 + sq * 8) =
        *(const bf16x8*)(Bm + (long)(n0 + srow) * K + k0 + sq * 8);
    __syncthreads();
    bf16x8 a = *(const bf16x8*)(As + (w * 16 + c) * 40 + q * 8);
#pragma unroll
    for (int nt = 0; nt < 4; ++nt) {
      bf16x8 b = *(const bf16x8*)(Bs + (nt * 16 + c) * 40 + q * 8);
      acc[nt] = __builtin_amdgcn_mfma_f32_16x16x32_bf16(a, b, acc[nt], 0, 0, 0);
    }
    __syncthreads();
  }
#pragma unroll
  for (int nt = 0; nt < 4; ++nt) {
    int n = n0 + nt * 16 + c;
    float bv = bias ? bias[n] : 0.f;
#pragma unroll
    for (int r = 0; r < 4; ++r) {
      int m = m0 + w * 16 + q * 4 + r;
      float v = acc[nt][r] + bv;
      long off;
      if (gimode) {
        int t = m & 127, b = m >> 7;
        int bg = b >> 2, br = b & 3;
        int dir = (n >= 768) ? 1 : 0;
        int rest = n - dir * 768;
        off = ((((long)t * 2 + dir) * 4 + bg) * 768 + rest) * 4 + br;
      } else {
        off = (long)m * ldc + n;
      }
      if (C) C[off] = v;
      if (Cbf) Cbf[off] = f2bf(v);
    }
  }
}

// ---------------- GRU scan: batch-split, fp8 weights in registers, bf16 gates ----------------
// grid (2 dirs, 4 batch-groups); 1024 thr = 16 waves; wave w owns gate-dim slice
// hd=w*16+c for all 3 gates -> Breg[8][3] = 24 longs = 48 VGPR. mg=4 batch rows/block
// sit in MFMA A rows 0..3 (rows 4..15 zero). Double-buffered h -> 1 barrier/step.
// gi3: [128][2][4][768][4] bf16 (r/z include b_ih+b_hh; n includes b_ih only)
__global__ __launch_bounds__(1024) void gru_scan(
    const u16* __restrict__ gi3,
    const u8* __restrict__ wf8l,        // [2][768][256] e4m3 this layer
    const float* __restrict__ bhhn_l,   // [2][256]
    const float* __restrict__ h0,       // [4][16][256]
    int layer, float* __restrict__ hn,  // [4][16][256]
    u16* __restrict__ ybf)              // [BL][512] bf16
{
  __shared__ u8 hq[2][16 * 264];  // e4m3 h state, double-buffered
  const int dir = blockIdx.x, bg = blockIdx.y;
  const int tid = threadIdx.x;
  const int w = tid >> 6, l = tid & 63, c = l & 15, q = l >> 4;
  const int hd = w * 16 + c;
  const u8* wdir = wf8l + (long)dir * 768 * 256;

  long Breg[8][3];
#pragma unroll
  for (int kt = 0; kt < 8; ++kt)
#pragma unroll
    for (int g = 0; g < 3; ++g)
      Breg[kt][g] = *(const long*)(wdir + (long)(g * 256 + hd) * 256 + kt * 32 + q * 8);
  const float bias_n = bhhn_l[dir * 256 + hd];

  // zero both h buffers (rows >= 4 stay zero forever)
  for (int e = tid; e < 1056; e += 1024) ((u64*)hq)[e] = 0ull;
  __syncthreads();

  float hprev[4] = {0.f, 0.f, 0.f, 0.f};
  const int hbase = (layer * 2 + dir) * (16 * 256);
  if (q == 0) {
#pragma unroll
    for (int r = 0; r < 4; ++r) {
      float v = h0[hbase + (bg * 4 + r) * 256 + hd];
      hprev[r] = v;
      hq[0][r * 264 + hd] = f2e4m3(v);
    }
  }

  const int tt0 = dir ? 127 : 0;
  const long gstep = dir ? -24576 : 24576;  // elements per t step
  const long ystep = dir ? -512 : 512;
  const u16* gp = gi3 + ((long)(tt0 * 2 + dir) * 4 + bg) * 3072;
  u16* yp = ybf + ((long)(bg * 4) * 128 + tt0) * 512 + dir * 256 + hd;

  // current-step gates (4 bf16 per gate = rows 0..3 of this thread's dim)
  u64 cg0 = *(const u64*)(gp + hd * 4);
  u64 cg1 = *(const u64*)(gp + 1024 + hd * 4);
  u64 cg2 = *(const u64*)(gp + 2048 + hd * 4);
  __syncthreads();

#pragma unroll 1
  for (int t = 0; t < 128; ++t) {
    f32x4 acc0, acc1, acc2;
    acc0[0] = bf2f((u16)cg0); acc0[1] = bf2f((u16)(cg0 >> 16));
    acc0[2] = bf2f((u16)(cg0 >> 32)); acc0[3] = bf2f((u16)(cg0 >> 48));
    acc1[0] = bf2f((u16)cg1); acc1[1] = bf2f((u16)(cg1 >> 16));
    acc1[2] = bf2f((u16)(cg1 >> 32)); acc1[3] = bf2f((u16)(cg1 >> 48));
    acc2[0] = bias_n; acc2[1] = bias_n; acc2[2] = bias_n; acc2[3] = bias_n;

    // prefetch next step's gates (overlaps MFMA section)
    const u16* gpn = gp + gstep;
    u64 n0 = cg0, n1 = cg1, n2 = cg2;
    if (t < 127) {
      n0 = *(const u64*)(gpn + hd * 4);
      n1 = *(const u64*)(gpn + 1024 + hd * 4);
      n2 = *(const u64*)(gpn + 2048 + hd * 4);
    }

    const u8* hb = hq[t & 1];
#pragma unroll
    for (int kt = 0; kt < 8; ++kt) {
      long a = *(const long*)(hb + c * 264 + kt * 32 + q * 8);
      acc0 = __builtin_amdgcn_mfma_f32_16x16x32_fp8_fp8(a, Breg[kt][0], acc0, 0, 0, 0);
      acc1 = __builtin_amdgcn_mfma_f32_16x16x32_fp8_fp8(a, Breg[kt][1], acc1, 0, 0, 0);
      acc2 = __builtin_amdgcn_mfma_f32_16x16x32_fp8_fp8(a, Breg[kt][2], acc2, 0, 0, 0);
    }
    if (q == 0) {
      float hv4[4];
#pragma unroll
      for (int r = 0; r < 4; ++r) {
        float gin = bf2f((u16)(cg2 >> (16 * r)));
        float rg = sigm(acc0[r]);
        float zg = sigm(acc1[r]);
        float ng = tanh_s(gin + rg * acc2[r]);
        float hv = (1.f - zg) * ng + zg * hprev[r];
        hprev[r] = hv;
        hv4[r] = hv;
        yp[r * 65536] = f2bf(hv);
      }
      int pk01 = __builtin_amdgcn_cvt_pk_fp8_f32(hv4[0], hv4[1], 0, false);
      int pk23 = __builtin_amdgcn_cvt_pk_fp8_f32(hv4[2], hv4[3], 0, false);
      u8* hw = hq[(t + 1) & 1];
      hw[0 * 264 + hd] = (u8)(pk01 & 0xff);
      hw[1 * 264 + hd] = (u8)((pk01 >> 8) & 0xff);
      hw[2 * 264 + hd] = (u8)(pk23 & 0xff);
      hw[3 * 264 + hd] = (u8)((pk23 >> 8) & 0xff);
    }
    cg0 = n0; cg1 = n1; cg2 = n2;
    gp = gpn;
    yp += ystep;
    __syncthreads();
  }
  if (q == 0) {
#pragma unroll
    for (int r = 0; r < 4; ++r)
      hn[hbase + (bg * 4 + r) * 256 + hd] = hprev[r];
  }
}

// ---------------- attention softmax ----------------
__global__ void attn_kernel(const float* __restrict__ hn, const float* __restrict__ wlp,
                            const float* __restrict__ blp, const float* __restrict__ outsq,
                            float* __restrict__ attw) {
  int b = blockIdx.x, tid = threadIdx.x;
  __shared__ float hsq[256];
  __shared__ float sc[128];
  __shared__ float red[2];
  {
    float s = blp[0];
#pragma unroll
    for (int d = 0; d < 4; ++d) s += hn[d * 4096 + b * 256 + tid] * wlp[d];
    hsq[tid] = s;
  }
  __syncthreads();
  if (tid < 128) {
    float s = 0.f;
    const float* op = outsq + (long)(b * 128 + tid) * 256;
    for (int h = 0; h < 256; ++h) s += hsq[h] * op[h];
    sc[tid] = s;
  }
  __syncthreads();
  if (tid == 0) {
    float m = sc[0];
    for (int i = 1; i < 128; ++i) m = fmaxf(m, sc[i]);
    red[0] = m;
  }
  __syncthreads();
  if (tid < 128) sc[tid] = __expf(sc[tid] - red[0]);
  __syncthreads();
  if (tid == 0) {
    float s = 0.f;
    for (int i = 0; i < 128; ++i) s += sc[i];
    red[1] = s;
  }
  __syncthreads();
  if (tid < 128) attw[b * 128 + tid] = sc[tid] / red[1];
}

// ---------------- build rel_in (bf16, K padded to 576) ----------------
__global__ void build_relin(const u16* __restrict__ outbf, const int* __restrict__ tags,
                            const float* __restrict__ emb_tok, const float* __restrict__ attw,
                            u16* __restrict__ relin) {
  int i = blockIdx.x * 256 + threadIdx.x;
  if (i >= BL * 576) return;
  int bl = i / 576, cc = i % 576;
  u16 v;
  if (cc < 512) v = outbf[(long)bl * 512 + cc];
  else if (cc < 544) v = f2bf(emb_tok[tags[bl] * 32 + (cc - 512)]);
  else if (cc == 544) v = f2bf(attw[bl]);
  else v = 0;
  relin[i] = v;
}

// ---------------- ner scores [BL][10] ----------------
__global__ __launch_bounds__(256) void ner_kernel(
    const u16* __restrict__ outbf, const float* __restrict__ attw,
    const float* __restrict__ wner, const float* __restrict__ bner,
    float* __restrict__ ner) {
  __shared__ float wn[10 * 513];
  int tid = threadIdx.x;
  for (int e = tid; e < 5130; e += 256) wn[e] = wner[e];
  __syncthreads();
  int row0 = blockIdx.x * 64;
  for (int o = tid; o < 640; o += 256) {
    int rr = o / 10, t = o % 10;
    int row = row0 + rr;
    const u16* op = outbf + (long)row * 512;
    const float* wp = wn + t * 513;
    float s = bner[t] + attw[row] * wp[512];
    for (int k = 0; k < 512; ++k) s += bf2f(op[k]) * wp[k];
    ner[(long)row * 10 + t] = s;
  }
}

// ---------------- fused rel-branch BCE over 32x32 pair tiles ----------------
__global__ __launch_bounds__(512) void rel_kernel(
    const float* __restrict__ AC,    // [BL][256]: cols 0:128 = A(u-part, j), 128:256 = C(v-part, i)
    const int* __restrict__ gold,    // [16][128][128]
    const float* __restrict__ mask,  // [16][128]
    const float* __restrict__ embr,  // [24][128]
    float* __restrict__ acc_out) {
  __shared__ float Au[32 * 132];
  __shared__ float Cv[32 * 132];
  __shared__ float ER[24 * 128];
  __shared__ int GT[32 * 33];
  __shared__ float Mi[32], Mj[32];
  __shared__ float redbuf[8];
  int b = blockIdx.x, it = blockIdx.y, jt = blockIdx.z;
  int i0 = it * 32, j0 = jt * 32;
  int tid = threadIdx.x;
  for (int e = tid; e < 4096; e += 512) {
    int rr = e >> 7, h = e & 127;
    Au[rr * 132 + h] = AC[(long)(b * 128 + j0 + rr) * 256 + h];
    Cv[rr * 132 + h] = AC[(long)(b * 128 + i0 + rr) * 256 + 128 + h];
  }
  for (int e = tid; e < 3072; e += 512) ER[e] = embr[e];
  for (int e = tid; e < 1024; e += 512) {
    int ii = e >> 5, jj = e & 31;
    GT[ii * 33 + jj] = gold[(long)b * 16384 + (i0 + ii) * 128 + (j0 + jj)];
  }
  if (tid < 32) Mi[tid] = mask[b * 128 + i0 + tid];
  else if (tid < 64) Mj[tid - 32] = mask[b * 128 + j0 + tid - 32];
  __syncthreads();
  float sum = 0.f;
#pragma unroll 1
  for (int k = 0; k < 2; ++k) {
    int p = tid + k * 512;
    int ii = p >> 5, jj = p & 31;
    float pm = Mi[ii] * Mj[jj];
    int g = GT[ii * 33 + jj];
    float logits[24];
#pragma unroll
    for (int r = 0; r < 24; ++r) logits[r] = 0.f;
#pragma unroll 1
    for (int hc = 0; hc < 4; ++hc) {
      float tt[32];
#pragma unroll
      for (int x4 = 0; x4 < 8; ++x4) {
        float4 a4 = *(const float4*)(Au + jj * 132 + hc * 32 + x4 * 4);
        float4 c4 = *(const float4*)(Cv + ii * 132 + hc * 32 + x4 * 4);
        tt[x4 * 4 + 0] = tanh_s(a4.x + c4.x);
        tt[x4 * 4 + 1] = tanh_s(a4.y + c4.y);
        tt[x4 * 4 + 2] = tanh_s(a4.z + c4.z);
        tt[x4 * 4 + 3] = tanh_s(a4.w + c4.w);
      }
#pragma unroll
      for (int r = 0; r < 24; ++r) {
        float s = logits[r];
#pragma unroll
        for (int x4 = 0; x4 < 8; ++x4) {
          float4 e4 = *(const float4*)(ER + r * 128 + hc * 32 + x4 * 4);
          s += tt[x4 * 4] * e4.x + tt[x4 * 4 + 1] * e4.y +
               tt[x4 * 4 + 2] * e4.z + tt[x4 * 4 + 3] * e4.w;
        }
        logits[r] = s;
      }
    }
    float lsum = 0.f;
#pragma unroll
    for (int r = 0; r < 24; ++r) {
      float x = logits[r];
      float e = __expf(-fabsf(x));
      float l1p = __logf(1.f + e);
      float lsp = fminf(x, 0.f) - l1p;   // log_sigmoid(x)
      float lsn = fminf(-x, 0.f) - l1p;  // log_sigmoid(-x)
      float wr = r ? 50.f : 1.f;
      float pw = r ? 20.f : 1.f;
      lsum -= (r == g) ? (wr * pw * lsp) : (wr * lsn);
    }
    sum += lsum * pm;
  }
  for (int off = 32; off > 0; off >>= 1) sum += __shfl_down(sum, off, 64);
  if ((tid & 63) == 0) redbuf[tid >> 6] = sum;
  __syncthreads();
  if (tid == 0) {
    float s = 0.f;
    for (int x = 0; x < 8; ++x) s += redbuf[x];
    atomicAdd(acc_out, s);
  }
}

// ---------------- CRF log-likelihood (numerator + forward algo) ----------------
__global__ __launch_bounds__(512) void crf_kernel(
    const float* __restrict__ ner, const int* __restrict__ tags,
    const float* __restrict__ mask, const float* __restrict__ cs,
    const float* __restrict__ ct, const float* __restrict__ ce,
    float* __restrict__ scal) {
  __shared__ float tr[100];
  __shared__ float alpha[2][16][12];
  __shared__ float logZ[16], sc[16];
  __shared__ float red[8];
  int tid = threadIdx.x;
  if (tid < 100) tr[tid] = ct[tid];
  __syncthreads();
  int b = tid / 10, j = tid % 10;
  if (tid < 160) alpha[0][b][j] = cs[j] + ner[(long)(b * 128) * 10 + j];
  __syncthreads();
  int cur = 0;
  for (int t = 1; t < 128; ++t) {
    if (tid < 160) {
      float m = -1e30f;
#pragma unroll
      for (int i = 0; i < 10; ++i) m = fmaxf(m, alpha[cur][b][i] + tr[i * 10 + j]);
      float s = 0.f;
#pragma unroll
      for (int i = 0; i < 10; ++i) s += __expf(alpha[cur][b][i] + tr[i * 10 + j] - m);
      float v = m + __logf(s) + ner[(long)(b * 128 + t) * 10 + j];
      float mk = mask[b * 128 + t];
      alpha[1 - cur][b][j] = (mk > 0.f) ? v : alpha[cur][b][j];
    }
    __syncthreads();
    cur ^= 1;
  }
  if (tid < 16) {
    int bb = tid;
    float m = -1e30f;
    for (int jj = 0; jj < 10; ++jj) m = fmaxf(m, alpha[cur][bb][jj] + ce[jj]);
    float s = 0.f;
    for (int jj = 0; jj < 10; ++jj) s += __expf(alpha[cur][bb][jj] + ce[jj] - m);
    logZ[bb] = m + __logf(s);
    int tprev = tags[bb * 128];
    float sco = cs[tprev] + ner[(long)(bb * 128) * 10 + tprev];
    float msum_b = mask[bb * 128];
    for (int t = 1; t < 128; ++t) {
      int tc = tags[bb * 128 + t];
      float mk = mask[bb * 128 + t];
      sco += (tr[tprev * 10 + tc] + ner[(long)(bb * 128 + t) * 10 + tc]) * mk;
      msum_b += mk;
      tprev = tc;
    }
    int send = (int)(msum_b)-1;
    int last = tags[bb * 128 + send];
    sco += ce[last];
    sc[bb] = sco - logZ[bb];
  }
  float ms = 0.f;
  for (int e = tid; e < 2048; e += 512) ms += mask[e];
  for (int off = 32; off > 0; off >>= 1) ms += __shfl_down(ms, off, 64);
  if ((tid & 63) == 0) red[tid >> 6] = ms;
  __syncthreads();
  if (tid == 0) {
    float s = 0.f;
    for (int x = 0; x < 8; ++x) s += red[x];
    scal[1] = s;
    float llh = 0.f;
    for (int bb = 0; bb < 16; ++bb) llh += sc[bb];
    scal[0] = llh;
  }
}

__global__ void finalize_kernel(const float* __restrict__ scal, float* __restrict__ out) {
  if (threadIdx.x == 0 && blockIdx.x == 0) {
    out[0] = -scal[0];
    out[1] = scal[2] / scal[1];
  }
}

// ---------------- host launch ----------------
extern "C" void kernel_launch(void* const* d_in, const int* in_sizes, int n_in,
                              void* d_out, int out_size, void* d_ws, size_t ws_size,
                              hipStream_t stream) {
  (void)in_sizes; (void)n_in; (void)out_size; (void)ws_size;
  const int*   text = (const int*)d_in[0];
  const int*   tags = (const int*)d_in[1];
  const int*   gold = (const int*)d_in[2];
  const float* mask = (const float*)d_in[3];
  const float* h0   = (const float*)d_in[4];
  const float* embw = (const float*)d_in[5];
  const float* embt = (const float*)d_in[6];
  const float* embr = (const float*)d_in[7];
  const float* wih0 = (const float*)d_in[8];
  const float* whh0 = (const float*)d_in[9];
  const float* bih0 = (const float*)d_in[10];
  const float* bhh0 = (const float*)d_in[11];
  const float* wih1 = (const float*)d_in[12];
  const float* whh1 = (const float*)d_in[13];
  const float* bih1 = (const float*)d_in[14];
  const float* bhh1 = (const float*)d_in[15];
  const float* whp  = (const float*)d_in[16];
  const float* bhp  = (const float*)d_in[17];
  const float* wlp  = (const float*)d_in[18];
  const float* blp  = (const float*)d_in[19];
  const float* wner = (const float*)d_in[20];
  const float* bner = (const float*)d_in[21];
  const float* cs   = (const float*)d_in[22];
  const float* ct   = (const float*)d_in[23];
  const float* ce   = (const float*)d_in[24];
  const float* wu   = (const float*)d_in[25];
  const float* bu   = (const float*)d_in[26];
  const float* wv   = (const float*)d_in[27];
  const float* bv   = (const float*)d_in[28];
  const float* wuv  = (const float*)d_in[29];
  const float* buv  = (const float*)d_in[30];

  char* ws = (char*)d_ws;
  u16*   gi     = (u16*)(ws + 0);           // [128][2][4][768][4] bf16 (6.29 MB)
  u16*   xbf    = (u16*)(ws + 12582912);
  u16*   y0bf   = (u16*)(ws + 13631488);
  u8*    wf8    = (u8*)(ws + 15728640);     // [2][2][768][256] e4m3 (786432 B)
  float* bc     = (float*)(ws + 16515072);  // [2][1536] fused GEMM bias
  float* bhhn   = (float*)(ws + 16527360);  // [2][512] n-gate hh bias
  u16*   outbf  = (u16*)(ws + 19922944);
  float* hn     = (float*)(ws + 22020096);
  float* outsq  = (float*)(ws + 22085632);
  float* attw   = (float*)(ws + 24182784);
  u16*   relin  = (u16*)(ws + 24190976);
  u16*   uvbf   = (u16*)(ws + 28647424);
  float* ac32   = (float*)(ws + 29696000);
  float* ner    = (float*)(ws + 31793152);
  u16*   wih0b  = (u16*)(ws + 31875072);
  u16*   wih1b  = (u16*)(ws + 32661504);
  u16*   whpb   = (u16*)(ws + 34234368);
  u16*   wuvp   = (u16*)(ws + 34496512);
  u16*   wuvc   = (u16*)(ws + 34791424);
  float* buv2   = (float*)(ws + 34856960);
  float* scal   = (float*)(ws + 34859008);

  prep_kernel<<<8913, 256, 0, stream>>>(wih0, wih1, whp, wu, wv, wuv, bu, bv,
                                        whh0, whh1, bih0, bhh0, bih1, bhh1,
                                        wih0b, wih1b, whpb, wuvp, wuvc, buv2, scal,
                                        wf8, bc, bhhn);
  gather_x<<<2048, 256, 0, stream>>>(text, embw, xbf);
  gemm_bf16<<<dim3(32, 24), 256, 0, stream>>>(xbf, 256, wih0b, bc, nullptr, gi, 1536, 2048, 1536, 256, 1);
  gru_scan<<<dim3(2, 4), 1024, 0, stream>>>(gi, wf8, bhhn, h0, 0, hn, y0bf);
  gemm_bf16<<<dim3(32, 24), 256, 0, stream>>>(y0bf, 512, wih1b, bc + 1536, nullptr, gi, 1536, 2048, 1536, 512, 1);
  gru_scan<<<dim3(2, 4), 1024, 0, stream>>>(gi, wf8 + 393216, bhhn + 512, h0, 1, hn, outbf);
  gemm_bf16<<<dim3(32, 4), 256, 0, stream>>>(outbf, 512, whpb, bhp, outsq, nullptr, 256, 2048, 256, 512, 0);
  attn_kernel<<<16, 256, 0, stream>>>(hn, wlp, blp, outsq, attw);
  build_relin<<<4608, 256, 0, stream>>>(outbf, tags, embt, attw, relin);
  ner_kernel<<<32, 256, 0, stream>>>(outbf, attw, wner, bner, ner);
  gemm_bf16<<<dim3(32, 4), 256, 0, stream>>>(relin, 576, wuvp, buv2, nullptr, uvbf, 256, 2048, 256, 576, 0);
  // AC = [U @ wuv_u^T | V @ wuv_v^T + b_uv]
  gemm_bf16<<<dim3(32, 2), 256, 0, stream>>>(uvbf, 256, wuvc, nullptr, ac32, nullptr, 256, 2048, 128, 128, 0);
  gemm_bf16<<<dim3(32, 2), 256, 0, stream>>>(uvbf + 128, 256, wuvc + 128 * 128, buv, ac32 + 128, nullptr, 256, 2048, 128, 128, 0);
  rel_kernel<<<dim3(16, 4, 4), 512, 0, stream>>>(ac32, gold, mask, embr, scal + 2);
  crf_kernel<<<1, 512, 0, stream>>>(ner, tags, mask, cs, ct, ce, scal);
  finalize_kernel<<<1, 64, 0, stream>>>(scal, (float*)d_out);
}

// Round 8
// 837.478 us; speedup vs baseline: 1.3675x; 1.2124x over previous
//
#include <hip/hip_runtime.h>

typedef unsigned short u16;
typedef unsigned char u8;
typedef unsigned long long u64;
typedef __attribute__((ext_vector_type(4))) float f32x4;
typedef __attribute__((ext_vector_type(8))) short bf16x8;

#define BL 2048   // B*L

__device__ __forceinline__ u16 f2bf(float f) {
  unsigned u = __float_as_uint(f);
  u += 0x7fffu + ((u >> 16) & 1u);
  return (u16)(u >> 16);
}
__device__ __forceinline__ float bf2f(u16 x) {
  return __uint_as_float(((unsigned)x) << 16);
}
// float -> OCP e4m3fn (RNE, saturate to 448) — software path (prep/init only)
__device__ __forceinline__ u8 f2e4m3(float f) {
  unsigned u = __float_as_uint(f);
  unsigned s = (u >> 24) & 0x80u;
  float a = fabsf(f);
  a = fminf(a, 448.f);
  if (a < 0.015625f) {
    int m = (int)(a * 512.f + 0.5f);
    return (u8)(s | (unsigned)m);
  }
  unsigned au = __float_as_uint(a);
  au += 0x7ffffu + ((au >> 20) & 1u);
  unsigned e = (au >> 23) - 127u + 7u;
  unsigned m = (au >> 20) & 7u;
  return (u8)(s | (e << 3) | m);
}
__device__ __forceinline__ float sigm(float x) {
  float e = __expf(-fabsf(x));
  float s = 1.f / (1.f + e);
  return x >= 0.f ? s : 1.f - s;
}
__device__ __forceinline__ float tanh_s(float x) {
  float e = __expf(-2.f * fabsf(x));
  float t = (1.f - e) / (1.f + e);
  return x >= 0.f ? t : -t;
}

// ---------------- prep: weight conversions + fused biases + zero scalars ----------------
__global__ void prep_kernel(const float* __restrict__ wih0, const float* __restrict__ wih1,
                            const float* __restrict__ whp, const float* __restrict__ wu,
                            const float* __restrict__ wv, const float* __restrict__ wuv,
                            const float* __restrict__ bu, const float* __restrict__ bv,
                            const float* __restrict__ whh0, const float* __restrict__ whh1,
                            const float* __restrict__ bih0, const float* __restrict__ bhh0,
                            const float* __restrict__ bih1, const float* __restrict__ bhh1,
                            u16* __restrict__ o_wih0, u16* __restrict__ o_wih1,
                            u16* __restrict__ o_whp, u16* __restrict__ o_wuvpad,
                            u16* __restrict__ o_wuvc, float* __restrict__ o_buv2,
                            float* __restrict__ scal, u8* __restrict__ o_wf8,
                            float* __restrict__ o_bc, float* __restrict__ o_bhhn) {
  long i = (long)blockIdx.x * 256 + threadIdx.x;
  const long c1 = 393216, c2 = 1179648, c3 = 1310720, c4 = 1458176,
             c5 = 1490944, c6 = 1491200, c7 = 1491216,
             c8 = 2277648, c9 = 2280720, c10 = 2281744;
  if (i < c1) { o_wih0[i] = f2bf(wih0[i]); return; }
  if (i < c2) { long j = i - c1; o_wih1[j] = f2bf(wih1[j]); return; }
  if (i < c3) { long j = i - c2; o_whp[j] = f2bf(whp[j]); return; }
  if (i < c4) {
    long j = i - c3; int n = (int)(j / 576), k = (int)(j % 576);
    float v = 0.f;
    if (k < 545) v = (n < 128) ? wu[n * 545 + k] : wv[(n - 128) * 545 + k];
    o_wuvpad[j] = f2bf(v); return;
  }
  if (i < c5) {
    long j = i - c4; int n = (int)(j / 128), k = (int)(j % 128);
    float v = (n < 128) ? wuv[n * 256 + k] : wuv[(n - 128) * 256 + 128 + k];
    o_wuvc[j] = f2bf(v); return;
  }
  if (i < c6) { int n = (int)(i - c5); o_buv2[n] = (n < 128) ? bu[n] : bv[n - 128]; return; }
  if (i < c7) { scal[i - c6] = 0.f; return; }
  if (i < c8) {  // wf8[2 layers][2 dirs][768][256] e4m3
    long j = i - c7;
    int layer = (int)(j / 393216);
    long r = j % 393216;
    float v = layer ? whh1[r] : whh0[r];
    o_wf8[j] = f2e4m3(v); return;
  }
  if (i < c9) {  // bc[2 layers][2 dirs][768]: bih + (g<2 ? bhh : 0)
    long j = i - c8;
    int layer = (int)(j / 1536);
    int k2 = (int)(j % 1536);
    float v = (layer ? bih1[k2] : bih0[k2]);
    if ((k2 % 768) < 512) v += (layer ? bhh1[k2] : bhh0[k2]);
    o_bc[j] = v; return;
  }
  if (i < c10) {  // bhhn[2 layers][2 dirs][256] = bhh n-gate part
    long j = i - c9;
    int layer = (int)(j / 512);
    int k3 = (int)(j % 512);
    int idx = (k3 / 256) * 768 + 512 + (k3 % 256);
    o_bhhn[j] = layer ? bhh1[idx] : bhh0[idx];
    return;
  }
}

// ---------------- embedding gather -> bf16 ----------------
__global__ void gather_x(const int* __restrict__ text, const float* __restrict__ embw,
                         u16* __restrict__ xbf) {
  int i = blockIdx.x * 256 + threadIdx.x;
  if (i >= BL * 256) return;
  int bl = i >> 8, k = i & 255;
  xbf[i] = f2bf(embw[(long)text[bl] * 256 + k]);
}

// ---------------- generic bf16 MFMA GEMM: C[M,N] = A[M,K] @ B[N,K]^T + bias ----------------
// gimode=1: write bf16 gates in layout [t][dir][bg][3 gates][4 rows][256 dims]
__global__ __launch_bounds__(256) void gemm_bf16(
    const u16* __restrict__ A, int lda, const u16* __restrict__ Bm,
    const float* __restrict__ bias, float* __restrict__ C, u16* __restrict__ Cbf,
    int ldc, int M, int N, int K, int gimode) {
  __shared__ u16 As[64 * 40];
  __shared__ u16 Bs[64 * 40];
  const int tid = threadIdx.x;
  const int w = tid >> 6, l = tid & 63, c = l & 15, q = l >> 4;
  const int m0 = blockIdx.x * 64, n0 = blockIdx.y * 64;
  const int srow = tid >> 2, sq = tid & 3;
  f32x4 zero = {0.f, 0.f, 0.f, 0.f};
  f32x4 acc[4] = {zero, zero, zero, zero};
  for (int k0 = 0; k0 < K; k0 += 32) {
    *(bf16x8*)(As + srow * 40 + sq * 8) =
        *(const bf16x8*)(A + (long)(m0 + srow) * lda + k0 + sq * 8);
    *(bf16x8*)(Bs + srow * 40 + sq * 8) =
        *(const bf16x8*)(Bm + (long)(n0 + srow) * K + k0 + sq * 8);
    __syncthreads();
    bf16x8 a = *(const bf16x8*)(As + (w * 16 + c) * 40 + q * 8);
#pragma unroll
    for (int nt = 0; nt < 4; ++nt) {
      bf16x8 b = *(const bf16x8*)(Bs + (nt * 16 + c) * 40 + q * 8);
      acc[nt] = __builtin_amdgcn_mfma_f32_16x16x32_bf16(a, b, acc[nt], 0, 0, 0);
    }
    __syncthreads();
  }
#pragma unroll
  for (int nt = 0; nt < 4; ++nt) {
    int n = n0 + nt * 16 + c;
    float bv = bias ? bias[n] : 0.f;
#pragma unroll
    for (int r = 0; r < 4; ++r) {
      int m = m0 + w * 16 + q * 4 + r;
      float v = acc[nt][r] + bv;
      long off;
      if (gimode) {
        int t = m & 127, b = m >> 7;
        int dir = (n >= 768) ? 1 : 0;
        int rest = n - dir * 768;
        int g = rest >> 8, d = rest & 255;
        off = ((((long)t * 2 + dir) * 4 + (b >> 2)) * 3 + g) * 1024 + (b & 3) * 256 + d;
      } else {
        off = (long)m * ldc + n;
      }
      if (C) C[off] = v;
      if (Cbf) Cbf[off] = f2bf(v);
    }
  }
}

// ---------------- GRU scan: fp8 weights in regs, dense 1-elem/thread epilogue ----------------
// grid (2 dirs, 4 batch-groups); 1024 thr = 16 waves. MFMA phase: wave w owns gate-dim
// slice hd=w*16+c for all 3 gates (Breg[8][3] = 48 VGPR), M rows 0..3 = batch. Epilogue
// phase: thread (er=tid>>8, ed=tid&255) owns ONE h element -> all transcendentals dense,
// hprev in a scalar register. Acc crosses phases via small LDS buffer.
// gi4: [128][2][4][3][4][256] bf16 (r/z gates include b_ih+b_hh; n includes b_ih only)
__global__ __launch_bounds__(1024) void gru_scan(
    const u16* __restrict__ gi4,
    const u8* __restrict__ wf8l,        // [2][768][256] e4m3 this layer
    const float* __restrict__ bhhn_l,   // [2][256]
    const float* __restrict__ h0,       // [4][16][256]
    int layer, float* __restrict__ hn,  // [4][16][256]
    u16* __restrict__ ybf)              // [BL][512] bf16
{
  __shared__ u8 hq[2][16 * 264];      // e4m3 h state, double-buffered (rows>=4 stay 0)
  __shared__ float accs[3][4][264];   // [gate][row][dim+pad] cross-phase buffer
  const int dir = blockIdx.x, bg = blockIdx.y;
  const int tid = threadIdx.x;
  const int w = tid >> 6, l = tid & 63, c = l & 15, q = l >> 4;
  const int hd = w * 16 + c;
  const u8* wdir = wf8l + (long)dir * 768 * 256;

  long Breg[8][3];
#pragma unroll
  for (int kt = 0; kt < 8; ++kt)
#pragma unroll
    for (int g = 0; g < 3; ++g)
      Breg[kt][g] = *(const long*)(wdir + (long)(g * 256 + hd) * 256 + kt * 32 + q * 8);

  const int er = tid >> 8, ed = tid & 255;  // epilogue identity: row, dim
  const float bias_n = bhhn_l[dir * 256 + ed];
  const int hbase = (layer * 2 + dir) * (16 * 256);

  for (int e = tid; e < 1056; e += 1024) ((u64*)hq)[e] = 0ull;
  __syncthreads();
  float hprev = h0[hbase + (bg * 4 + er) * 256 + ed];
  hq[0][er * 264 + ed] = f2e4m3(hprev);

  const int tt0 = dir ? 127 : 0;
  const long gstep = dir ? -24576 : 24576;
  const long ystep = dir ? -512 : 512;
  const u16* gp = gi4 + ((long)(tt0 * 2 + dir) * 4 + bg) * 3072 + er * 256 + ed;
  u16* yp = ybf + ((long)((bg * 4 + er) * 128) + tt0) * 512 + dir * 256 + ed;

  // 2-deep gate prefetch ring (no register copies: manual 2x unroll alternates A/B)
  u16 gAr = gp[0], gAz = gp[1024], gAn = gp[2048];
  const u16* gp1 = gp + gstep;
  u16 gBr = gp1[0], gBz = gp1[1024], gBn = gp1[2048];
  const u16* gpp = gp + 2 * gstep;
  __syncthreads();

#pragma unroll 1
  for (int t = 0; t < 128; t += 2) {
    // ======== even step: reads hq[0], writes hq[1] ========
    {
      f32x4 a0 = {0.f, 0.f, 0.f, 0.f}, a1 = a0, a2 = a0;
#pragma unroll
      for (int kt = 0; kt < 8; ++kt) {
        long a = *(const long*)(hq[0] + c * 264 + kt * 32 + q * 8);
        a0 = __builtin_amdgcn_mfma_f32_16x16x32_fp8_fp8(a, Breg[kt][0], a0, 0, 0, 0);
        a1 = __builtin_amdgcn_mfma_f32_16x16x32_fp8_fp8(a, Breg[kt][1], a1, 0, 0, 0);
        a2 = __builtin_amdgcn_mfma_f32_16x16x32_fp8_fp8(a, Breg[kt][2], a2, 0, 0, 0);
      }
      if (q == 0) {
#pragma unroll
        for (int r = 0; r < 4; ++r) {
          accs[0][r][hd] = a0[r];
          accs[1][r][hd] = a1[r];
          accs[2][r][hd] = a2[r];
        }
      }
      __syncthreads();
      float rg = sigm(bf2f(gAr) + accs[0][er][ed]);
      float zg = sigm(bf2f(gAz) + accs[1][er][ed]);
      float ng = tanh_s(bf2f(gAn) + rg * (accs[2][er][ed] + bias_n));
      float hv = (1.f - zg) * ng + zg * hprev;
      hprev = hv;
      yp[0] = f2bf(hv);
      hq[1][er * 264 + ed] =
          (u8)(__builtin_amdgcn_cvt_pk_fp8_f32(hv, hv, 0, false) & 0xff);
      if (t < 126) { gAr = gpp[0]; gAz = gpp[1024]; gAn = gpp[2048]; gpp += gstep; }
      yp += ystep;
      __syncthreads();
    }
    // ======== odd step: reads hq[1], writes hq[0] ========
    {
      f32x4 a0 = {0.f, 0.f, 0.f, 0.f}, a1 = a0, a2 = a0;
#pragma unroll
      for (int kt = 0; kt < 8; ++kt) {
        long a = *(const long*)(hq[1] + c * 264 + kt * 32 + q * 8);
        a0 = __builtin_amdgcn_mfma_f32_16x16x32_fp8_fp8(a, Breg[kt][0], a0, 0, 0, 0);
        a1 = __builtin_amdgcn_mfma_f32_16x16x32_fp8_fp8(a, Breg[kt][1], a1, 0, 0, 0);
        a2 = __builtin_amdgcn_mfma_f32_16x16x32_fp8_fp8(a, Breg[kt][2], a2, 0, 0, 0);
      }
      if (q == 0) {
#pragma unroll
        for (int r = 0; r < 4; ++r) {
          accs[0][r][hd] = a0[r];
          accs[1][r][hd] = a1[r];
          accs[2][r][hd] = a2[r];
        }
      }
      __syncthreads();
      float rg = sigm(bf2f(gBr) + accs[0][er][ed]);
      float zg = sigm(bf2f(gBz) + accs[1][er][ed]);
      float ng = tanh_s(bf2f(gBn) + rg * (accs[2][er][ed] + bias_n));
      float hv = (1.f - zg) * ng + zg * hprev;
      hprev = hv;
      yp[0] = f2bf(hv);
      hq[0][er * 264 + ed] =
          (u8)(__builtin_amdgcn_cvt_pk_fp8_f32(hv, hv, 0, false) & 0xff);
      if (t < 125) { gBr = gpp[0]; gBz = gpp[1024]; gBn = gpp[2048]; gpp += gstep; }
      yp += ystep;
      __syncthreads();
    }
  }
  hn[hbase + (bg * 4 + er) * 256 + ed] = hprev;
}

// ---------------- attention softmax ----------------
__global__ void attn_kernel(const float* __restrict__ hn, const float* __restrict__ wlp,
                            const float* __restrict__ blp, const float* __restrict__ outsq,
                            float* __restrict__ attw) {
  int b = blockIdx.x, tid = threadIdx.x;
  __shared__ float hsq[256];
  __shared__ float sc[128];
  __shared__ float red[2];
  {
    float s = blp[0];
#pragma unroll
    for (int d = 0; d < 4; ++d) s += hn[d * 4096 + b * 256 + tid] * wlp[d];
    hsq[tid] = s;
  }
  __syncthreads();
  if (tid < 128) {
    float s = 0.f;
    const float* op = outsq + (long)(b * 128 + tid) * 256;
    for (int h = 0; h < 256; ++h) s += hsq[h] * op[h];
    sc[tid] = s;
  }
  __syncthreads();
  if (tid == 0) {
    float m = sc[0];
    for (int i = 1; i < 128; ++i) m = fmaxf(m, sc[i]);
    red[0] = m;
  }
  __syncthreads();
  if (tid < 128) sc[tid] = __expf(sc[tid] - red[0]);
  __syncthreads();
  if (tid == 0) {
    float s = 0.f;
    for (int i = 0; i < 128; ++i) s += sc[i];
    red[1] = s;
  }
  __syncthreads();
  if (tid < 128) attw[b * 128 + tid] = sc[tid] / red[1];
}

// ---------------- build rel_in (bf16, K padded to 576) ----------------
__global__ void build_relin(const u16* __restrict__ outbf, const int* __restrict__ tags,
                            const float* __restrict__ emb_tok, const float* __restrict__ attw,
                            u16* __restrict__ relin) {
  int i = blockIdx.x * 256 + threadIdx.x;
  if (i >= BL * 576) return;
  int bl = i / 576, cc = i % 576;
  u16 v;
  if (cc < 512) v = outbf[(long)bl * 512 + cc];
  else if (cc < 544) v = f2bf(emb_tok[tags[bl] * 32 + (cc - 512)]);
  else if (cc == 544) v = f2bf(attw[bl]);
  else v = 0;
  relin[i] = v;
}

// ---------------- ner scores [BL][10] ----------------
__global__ __launch_bounds__(256) void ner_kernel(
    const u16* __restrict__ outbf, const float* __restrict__ attw,
    const float* __restrict__ wner, const float* __restrict__ bner,
    float* __restrict__ ner) {
  __shared__ float wn[10 * 513];
  int tid = threadIdx.x;
  for (int e = tid; e < 5130; e += 256) wn[e] = wner[e];
  __syncthreads();
  int row0 = blockIdx.x * 64;
  for (int o = tid; o < 640; o += 256) {
    int rr = o / 10, t = o % 10;
    int row = row0 + rr;
    const u16* op = outbf + (long)row * 512;
    const float* wp = wn + t * 513;
    float s = bner[t] + attw[row] * wp[512];
    for (int k = 0; k < 512; ++k) s += bf2f(op[k]) * wp[k];
    ner[(long)row * 10 + t] = s;
  }
}

// ---------------- fused rel-branch BCE over 32x32 pair tiles ----------------
__global__ __launch_bounds__(512) void rel_kernel(
    const float* __restrict__ AC,    // [BL][256]: cols 0:128 = A(u-part, j), 128:256 = C(v-part, i)
    const int* __restrict__ gold,    // [16][128][128]
    const float* __restrict__ mask,  // [16][128]
    const float* __restrict__ embr,  // [24][128]
    float* __restrict__ acc_out) {
  __shared__ float Au[32 * 132];
  __shared__ float Cv[32 * 132];
  __shared__ float ER[24 * 128];
  __shared__ int GT[32 * 33];
  __shared__ float Mi[32], Mj[32];
  __shared__ float redbuf[8];
  int b = blockIdx.x, it = blockIdx.y, jt = blockIdx.z;
  int i0 = it * 32, j0 = jt * 32;
  int tid = threadIdx.x;
  for (int e = tid; e < 4096; e += 512) {
    int rr = e >> 7, h = e & 127;
    Au[rr * 132 + h] = AC[(long)(b * 128 + j0 + rr) * 256 + h];
    Cv[rr * 132 + h] = AC[(long)(b * 128 + i0 + rr) * 256 + 128 + h];
  }
  for (int e = tid; e < 3072; e += 512) ER[e] = embr[e];
  for (int e = tid; e < 1024; e += 512) {
    int ii = e >> 5, jj = e & 31;
    GT[ii * 33 + jj] = gold[(long)b * 16384 + (i0 + ii) * 128 + (j0 + jj)];
  }
  if (tid < 32) Mi[tid] = mask[b * 128 + i0 + tid];
  else if (tid < 64) Mj[tid - 32] = mask[b * 128 + j0 + tid - 32];
  __syncthreads();
  float sum = 0.f;
#pragma unroll 1
  for (int k = 0; k < 2; ++k) {
    int p = tid + k * 512;
    int ii = p >> 5, jj = p & 31;
    float pm = Mi[ii] * Mj[jj];
    int g = GT[ii * 33 + jj];
    float logits[24];
#pragma unroll
    for (int r = 0; r < 24; ++r) logits[r] = 0.f;
#pragma unroll 1
    for (int hc = 0; hc < 4; ++hc) {
      float tt[32];
#pragma unroll
      for (int x4 = 0; x4 < 8; ++x4) {
        float4 a4 = *(const float4*)(Au + jj * 132 + hc * 32 + x4 * 4);
        float4 c4 = *(const float4*)(Cv + ii * 132 + hc * 32 + x4 * 4);
        tt[x4 * 4 + 0] = tanh_s(a4.x + c4.x);
        tt[x4 * 4 + 1] = tanh_s(a4.y + c4.y);
        tt[x4 * 4 + 2] = tanh_s(a4.z + c4.z);
        tt[x4 * 4 + 3] = tanh_s(a4.w + c4.w);
      }
#pragma unroll
      for (int r = 0; r < 24; ++r) {
        float s = logits[r];
#pragma unroll
        for (int x4 = 0; x4 < 8; ++x4) {
          float4 e4 = *(const float4*)(ER + r * 128 + hc * 32 + x4 * 4);
          s += tt[x4 * 4] * e4.x + tt[x4 * 4 + 1] * e4.y +
               tt[x4 * 4 + 2] * e4.z + tt[x4 * 4 + 3] * e4.w;
        }
        logits[r] = s;
      }
    }
    float lsum = 0.f;
#pragma unroll
    for (int r = 0; r < 24; ++r) {
      float x = logits[r];
      float e = __expf(-fabsf(x));
      float l1p = __logf(1.f + e);
      float lsp = fminf(x, 0.f) - l1p;   // log_sigmoid(x)
      float lsn = fminf(-x, 0.f) - l1p;  // log_sigmoid(-x)
      float wr = r ? 50.f : 1.f;
      float pw = r ? 20.f : 1.f;
      lsum -= (r == g) ? (wr * pw * lsp) : (wr * lsn);
    }
    sum += lsum * pm;
  }
  for (int off = 32; off > 0; off >>= 1) sum += __shfl_down(sum, off, 64);
  if ((tid & 63) == 0) redbuf[tid >> 6] = sum;
  __syncthreads();
  if (tid == 0) {
    float s = 0.f;
    for (int x = 0; x < 8; ++x) s += redbuf[x];
    atomicAdd(acc_out, s);
  }
}

// ---------------- CRF log-likelihood (numerator + forward algo) ----------------
__global__ __launch_bounds__(512) void crf_kernel(
    const float* __restrict__ ner, const int* __restrict__ tags,
    const float* __restrict__ mask, const float* __restrict__ cs,
    const float* __restrict__ ct, const float* __restrict__ ce,
    float* __restrict__ scal) {
  __shared__ float tr[100];
  __shared__ float alpha[2][16][12];
  __shared__ float logZ[16], sc[16];
  __shared__ float red[8];
  int tid = threadIdx.x;
  if (tid < 100) tr[tid] = ct[tid];
  __syncthreads();
  int b = tid / 10, j = tid % 10;
  if (tid < 160) alpha[0][b][j] = cs[j] + ner[(long)(b * 128) * 10 + j];
  __syncthreads();
  int cur = 0;
  for (int t = 1; t < 128; ++t) {
    if (tid < 160) {
      float m = -1e30f;
#pragma unroll
      for (int i = 0; i < 10; ++i) m = fmaxf(m, alpha[cur][b][i] + tr[i * 10 + j]);
      float s = 0.f;
#pragma unroll
      for (int i = 0; i < 10; ++i) s += __expf(alpha[cur][b][i] + tr[i * 10 + j] - m);
      float v = m + __logf(s) + ner[(long)(b * 128 + t) * 10 + j];
      float mk = mask[b * 128 + t];
      alpha[1 - cur][b][j] = (mk > 0.f) ? v : alpha[cur][b][j];
    }
    __syncthreads();
    cur ^= 1;
  }
  if (tid < 16) {
    int bb = tid;
    float m = -1e30f;
    for (int jj = 0; jj < 10; ++jj) m = fmaxf(m, alpha[cur][bb][jj] + ce[jj]);
    float s = 0.f;
    for (int jj = 0; jj < 10; ++jj) s += __expf(alpha[cur][bb][jj] + ce[jj] - m);
    logZ[bb] = m + __logf(s);
    int tprev = tags[bb * 128];
    float sco = cs[tprev] + ner[(long)(bb * 128) * 10 + tprev];
    float msum_b = mask[bb * 128];
    for (int t = 1; t < 128; ++t) {
      int tc = tags[bb * 128 + t];
      float mk = mask[bb * 128 + t];
      sco += (tr[tprev * 10 + tc] + ner[(long)(bb * 128 + t) * 10 + tc]) * mk;
      msum_b += mk;
      tprev = tc;
    }
    int send = (int)(msum_b)-1;
    int last = tags[bb * 128 + send];
    sco += ce[last];
    sc[bb] = sco - logZ[bb];
  }
  float ms = 0.f;
  for (int e = tid; e < 2048; e += 512) ms += mask[e];
  for (int off = 32; off > 0; off >>= 1) ms += __shfl_down(ms, off, 64);
  if ((tid & 63) == 0) red[tid >> 6] = ms;
  __syncthreads();
  if (tid == 0) {
    float s = 0.f;
    for (int x = 0; x < 8; ++x) s += red[x];
    scal[1] = s;
    float llh = 0.f;
    for (int bb = 0; bb < 16; ++bb) llh += sc[bb];
    scal[0] = llh;
  }
}

__global__ void finalize_kernel(const float* __restrict__ scal, float* __restrict__ out) {
  if (threadIdx.x == 0 && blockIdx.x == 0) {
    out[0] = -scal[0];
    out[1] = scal[2] / scal[1];
  }
}

// ---------------- host launch ----------------
extern "C" void kernel_launch(void* const* d_in, const int* in_sizes, int n_in,
                              void* d_out, int out_size, void* d_ws, size_t ws_size,
                              hipStream_t stream) {
  (void)in_sizes; (void)n_in; (void)out_size; (void)ws_size;
  const int*   text = (const int*)d_in[0];
  const int*   tags = (const int*)d_in[1];
  const int*   gold = (const int*)d_in[2];
  const float* mask = (const float*)d_in[3];
  const float* h0   = (const float*)d_in[4];
  const float* embw = (const float*)d_in[5];
  const float* embt = (const float*)d_in[6];
  const float* embr = (const float*)d_in[7];
  const float* wih0 = (const float*)d_in[8];
  const float* whh0 = (const float*)d_in[9];
  const float* bih0 = (const float*)d_in[10];
  const float* bhh0 = (const float*)d_in[11];
  const float* wih1 = (const float*)d_in[12];
  const float* whh1 = (const float*)d_in[13];
  const float* bih1 = (const float*)d_in[14];
  const float* bhh1 = (const float*)d_in[15];
  const float* whp  = (const float*)d_in[16];
  const float* bhp  = (const float*)d_in[17];
  const float* wlp  = (const float*)d_in[18];
  const float* blp  = (const float*)d_in[19];
  const float* wner = (const float*)d_in[20];
  const float* bner = (const float*)d_in[21];
  const float* cs   = (const float*)d_in[22];
  const float* ct   = (const float*)d_in[23];
  const float* ce   = (const float*)d_in[24];
  const float* wu   = (const float*)d_in[25];
  const float* bu   = (const float*)d_in[26];
  const float* wv   = (const float*)d_in[27];
  const float* bv   = (const float*)d_in[28];
  const float* wuv  = (const float*)d_in[29];
  const float* buv  = (const float*)d_in[30];

  char* ws = (char*)d_ws;
  u16*   gi     = (u16*)(ws + 0);           // [128][2][4][3][4][256] bf16 (6.29 MB)
  u16*   xbf    = (u16*)(ws + 12582912);
  u16*   y0bf   = (u16*)(ws + 13631488);
  u8*    wf8    = (u8*)(ws + 15728640);     // [2][2][768][256] e4m3 (786432 B)
  float* bc     = (float*)(ws + 16515072);  // [2][1536] fused GEMM bias
  float* bhhn   = (float*)(ws + 16527360);  // [2][512] n-gate hh bias
  u16*   outbf  = (u16*)(ws + 19922944);
  float* hn     = (float*)(ws + 22020096);
  float* outsq  = (float*)(ws + 22085632);
  float* attw   = (float*)(ws + 24182784);
  u16*   relin  = (u16*)(ws + 24190976);
  u16*   uvbf   = (u16*)(ws + 28647424);
  float* ac32   = (float*)(ws + 29696000);
  float* ner    = (float*)(ws + 31793152);
  u16*   wih0b  = (u16*)(ws + 31875072);
  u16*   wih1b  = (u16*)(ws + 32661504);
  u16*   whpb   = (u16*)(ws + 34234368);
  u16*   wuvp   = (u16*)(ws + 34496512);
  u16*   wuvc   = (u16*)(ws + 34791424);
  float* buv2   = (float*)(ws + 34856960);
  float* scal   = (float*)(ws + 34859008);

  prep_kernel<<<8913, 256, 0, stream>>>(wih0, wih1, whp, wu, wv, wuv, bu, bv,
                                        whh0, whh1, bih0, bhh0, bih1, bhh1,
                                        wih0b, wih1b, whpb, wuvp, wuvc, buv2, scal,
                                        wf8, bc, bhhn);
  gather_x<<<2048, 256, 0, stream>>>(text, embw, xbf);
  gemm_bf16<<<dim3(32, 24), 256, 0, stream>>>(xbf, 256, wih0b, bc, nullptr, gi, 1536, 2048, 1536, 256, 1);
  gru_scan<<<dim3(2, 4), 1024, 0, stream>>>(gi, wf8, bhhn, h0, 0, hn, y0bf);
  gemm_bf16<<<dim3(32, 24), 256, 0, stream>>>(y0bf, 512, wih1b, bc + 1536, nullptr, gi, 1536, 2048, 1536, 512, 1);
  gru_scan<<<dim3(2, 4), 1024, 0, stream>>>(gi, wf8 + 393216, bhhn + 512, h0, 1, hn, outbf);
  gemm_bf16<<<dim3(32, 4), 256, 0, stream>>>(outbf, 512, whpb, bhp, outsq, nullptr, 256, 2048, 256, 512, 0);
  attn_kernel<<<16, 256, 0, stream>>>(hn, wlp, blp, outsq, attw);
  build_relin<<<4608, 256, 0, stream>>>(outbf, tags, embt, attw, relin);
  ner_kernel<<<32, 256, 0, stream>>>(outbf, attw, wner, bner, ner);
  gemm_bf16<<<dim3(32, 4), 256, 0, stream>>>(relin, 576, wuvp, buv2, nullptr, uvbf, 256, 2048, 256, 576, 0);
  // AC = [U @ wuv_u^T | V @ wuv_v^T + b_uv]
  gemm_bf16<<<dim3(32, 2), 256, 0, stream>>>(uvbf, 256, wuvc, nullptr, ac32, nullptr, 256, 2048, 128, 128, 0);
  gemm_bf16<<<dim3(32, 2), 256, 0, stream>>>(uvbf + 128, 256, wuvc + 128 * 128, buv, ac32 + 128, nullptr, 256, 2048, 128, 128, 0);
  rel_kernel<<<dim3(16, 4, 4), 512, 0, stream>>>(ac32, gold, mask, embr, scal + 2);
  crf_kernel<<<1, 512, 0, stream>>>(ner, tags, mask, cs, ct, ce, scal);
  finalize_kernel<<<1, 64, 0, stream>>>(scal, (float*)d_out);
}

// Round 9
// 750.948 us; speedup vs baseline: 1.5251x; 1.1152x over previous
//
#include <hip/hip_runtime.h>

typedef unsigned short u16;
typedef unsigned char u8;
typedef unsigned long long u64;
typedef __attribute__((ext_vector_type(4))) float f32x4;
typedef __attribute__((ext_vector_type(8))) short bf16x8;

#define BL 2048   // B*L

__device__ __forceinline__ u16 f2bf(float f) {
  unsigned u = __float_as_uint(f);
  u += 0x7fffu + ((u >> 16) & 1u);
  return (u16)(u >> 16);
}
__device__ __forceinline__ float bf2f(u16 x) {
  return __uint_as_float(((unsigned)x) << 16);
}
// float -> OCP e4m3fn (RNE, saturate to 448) — software path (prep/init only)
__device__ __forceinline__ u8 f2e4m3(float f) {
  unsigned u = __float_as_uint(f);
  unsigned s = (u >> 24) & 0x80u;
  float a = fabsf(f);
  a = fminf(a, 448.f);
  if (a < 0.015625f) {
    int m = (int)(a * 512.f + 0.5f);
    return (u8)(s | (unsigned)m);
  }
  unsigned au = __float_as_uint(a);
  au += 0x7ffffu + ((au >> 20) & 1u);
  unsigned e = (au >> 23) - 127u + 7u;
  unsigned m = (au >> 20) & 7u;
  return (u8)(s | (e << 3) | m);
}
__device__ __forceinline__ float sigm(float x) {
  float e = __expf(-fabsf(x));
  float s = 1.f / (1.f + e);
  return x >= 0.f ? s : 1.f - s;
}
__device__ __forceinline__ float tanh_s(float x) {
  float e = __expf(-2.f * fabsf(x));
  float t = (1.f - e) / (1.f + e);
  return x >= 0.f ? t : -t;
}

// ---------------- prep: weight conversions + fused biases + zero scalars ----------------
__global__ void prep_kernel(const float* __restrict__ wih0, const float* __restrict__ wih1,
                            const float* __restrict__ whp, const float* __restrict__ wu,
                            const float* __restrict__ wv, const float* __restrict__ wuv,
                            const float* __restrict__ bu, const float* __restrict__ bv,
                            const float* __restrict__ whh0, const float* __restrict__ whh1,
                            const float* __restrict__ bih0, const float* __restrict__ bhh0,
                            const float* __restrict__ bih1, const float* __restrict__ bhh1,
                            u16* __restrict__ o_wih0, u16* __restrict__ o_wih1,
                            u16* __restrict__ o_whp, u16* __restrict__ o_wuvpad,
                            u16* __restrict__ o_wuvc, float* __restrict__ o_buv2,
                            float* __restrict__ scal, u8* __restrict__ o_wf8,
                            float* __restrict__ o_bc, float* __restrict__ o_bhhn) {
  long i = (long)blockIdx.x * 256 + threadIdx.x;
  const long c1 = 393216, c2 = 1179648, c3 = 1310720, c4 = 1458176,
             c5 = 1490944, c6 = 1491200, c7 = 1491216,
             c8 = 2277648, c9 = 2280720, c10 = 2281744;
  if (i < c1) { o_wih0[i] = f2bf(wih0[i]); return; }
  if (i < c2) { long j = i - c1; o_wih1[j] = f2bf(wih1[j]); return; }
  if (i < c3) { long j = i - c2; o_whp[j] = f2bf(whp[j]); return; }
  if (i < c4) {
    long j = i - c3; int n = (int)(j / 576), k = (int)(j % 576);
    float v = 0.f;
    if (k < 545) v = (n < 128) ? wu[n * 545 + k] : wv[(n - 128) * 545 + k];
    o_wuvpad[j] = f2bf(v); return;
  }
  if (i < c5) {
    long j = i - c4; int n = (int)(j / 128), k = (int)(j % 128);
    float v = (n < 128) ? wuv[n * 256 + k] : wuv[(n - 128) * 256 + 128 + k];
    o_wuvc[j] = f2bf(v); return;
  }
  if (i < c6) { int n = (int)(i - c5); o_buv2[n] = (n < 128) ? bu[n] : bv[n - 128]; return; }
  if (i < c7) { scal[i - c6] = 0.f; return; }
  if (i < c8) {  // wf8[2 layers][2 dirs][768][256] e4m3
    long j = i - c7;
    int layer = (int)(j / 393216);
    long r = j % 393216;
    float v = layer ? whh1[r] : whh0[r];
    o_wf8[j] = f2e4m3(v); return;
  }
  if (i < c9) {  // bc[2 layers][2 dirs][768]: bih + (g<2 ? bhh : 0)
    long j = i - c8;
    int layer = (int)(j / 1536);
    int k2 = (int)(j % 1536);
    float v = (layer ? bih1[k2] : bih0[k2]);
    if ((k2 % 768) < 512) v += (layer ? bhh1[k2] : bhh0[k2]);
    o_bc[j] = v; return;
  }
  if (i < c10) {  // bhhn[2 layers][2 dirs][256] = bhh n-gate part
    long j = i - c9;
    int layer = (int)(j / 512);
    int k3 = (int)(j % 512);
    int idx = (k3 / 256) * 768 + 512 + (k3 % 256);
    o_bhhn[j] = layer ? bhh1[idx] : bhh0[idx];
    return;
  }
}

// ---------------- embedding gather -> bf16 ----------------
__global__ void gather_x(const int* __restrict__ text, const float* __restrict__ embw,
                         u16* __restrict__ xbf) {
  int i = blockIdx.x * 256 + threadIdx.x;
  if (i >= BL * 256) return;
  int bl = i >> 8, k = i & 255;
  xbf[i] = f2bf(embw[(long)text[bl] * 256 + k]);
}

// ---------------- generic bf16 MFMA GEMM: C[M,N] = A[M,K] @ B[N,K]^T + bias ----------------
// gimode=1: write bf16 gates in layout [t][dir][bg][3 gates][4 rows][256 dims]
__global__ __launch_bounds__(256) void gemm_bf16(
    const u16* __restrict__ A, int lda, const u16* __restrict__ Bm,
    const float* __restrict__ bias, float* __restrict__ C, u16* __restrict__ Cbf,
    int ldc, int M, int N, int K, int gimode) {
  __shared__ u16 As[64 * 40];
  __shared__ u16 Bs[64 * 40];
  const int tid = threadIdx.x;
  const int w = tid >> 6, l = tid & 63, c = l & 15, q = l >> 4;
  const int m0 = blockIdx.x * 64, n0 = blockIdx.y * 64;
  const int srow = tid >> 2, sq = tid & 3;
  f32x4 zero = {0.f, 0.f, 0.f, 0.f};
  f32x4 acc[4] = {zero, zero, zero, zero};
  for (int k0 = 0; k0 < K; k0 += 32) {
    *(bf16x8*)(As + srow * 40 + sq * 8) =
        *(const bf16x8*)(A + (long)(m0 + srow) * lda + k0 + sq * 8);
    *(bf16x8*)(Bs + srow * 40 + sq * 8) =
        *(const bf16x8*)(Bm + (long)(n0 + srow) * K + k0 + sq * 8);
    __syncthreads();
    bf16x8 a = *(const bf16x8*)(As + (w * 16 + c) * 40 + q * 8);
#pragma unroll
    for (int nt = 0; nt < 4; ++nt) {
      bf16x8 b = *(const bf16x8*)(Bs + (nt * 16 + c) * 40 + q * 8);
      acc[nt] = __builtin_amdgcn_mfma_f32_16x16x32_bf16(a, b, acc[nt], 0, 0, 0);
    }
    __syncthreads();
  }
#pragma unroll
  for (int nt = 0; nt < 4; ++nt) {
    int n = n0 + nt * 16 + c;
    float bv = bias ? bias[n] : 0.f;
#pragma unroll
    for (int r = 0; r < 4; ++r) {
      int m = m0 + w * 16 + q * 4 + r;
      float v = acc[nt][r] + bv;
      long off;
      if (gimode) {
        int t = m & 127, b = m >> 7;
        int dir = (n >= 768) ? 1 : 0;
        int rest = n - dir * 768;
        int g = rest >> 8, d = rest & 255;
        off = ((((long)t * 2 + dir) * 4 + (b >> 2)) * 3 + g) * 1024 + (b & 3) * 256 + d;
      } else {
        off = (long)m * ldc + n;
      }
      if (C) C[off] = v;
      if (Cbf) Cbf[off] = f2bf(v);
    }
  }
}

// ---------------- GRU scan: fp8 weights in regs, wave-local epilogue, 1 lgkm-barrier/step --
// grid (2 dirs, 4 batch-groups); 1024 thr = 16 waves. Wave w owns gate-dim slice
// hd=w*16+(l&15); MFMA C rows 0..3 (q==0 lanes) = the 4 batch rows. Epilogue: lane (q,c)
// owns element (row q, dim hd) -> accs LDS round-trip is WAVE-LOCAL (no barrier), and the
// single per-step barrier is a raw lgkmcnt-only s_barrier: global gate-prefetch loads and
// y-stores are never drained in-loop (vs __syncthreads' vmcnt(0) drain = ~2 HBM RTs/step).
// gi4: [128][2][4][3][4][256] bf16 (r/z gates include b_ih+b_hh; n includes b_ih only)
__global__ __launch_bounds__(1024) void gru_scan(
    const u16* __restrict__ gi4,
    const u8* __restrict__ wf8l,        // [2][768][256] e4m3 this layer
    const float* __restrict__ bhhn_l,   // [2][256]
    const float* __restrict__ h0,       // [4][16][256]
    int layer, float* __restrict__ hn,  // [4][16][256]
    u16* __restrict__ ybf)              // [BL][512] bf16
{
  __shared__ u8 hq[2][16 * 264];      // e4m3 h state, double-buffered (rows>=4 stay 0)
  __shared__ float accs[3][4][264];   // [gate][row][dim+pad], wave-local use only
  const int dir = blockIdx.x, bg = blockIdx.y;
  const int tid = threadIdx.x;
  const int w = tid >> 6, l = tid & 63, c = l & 15, q = l >> 4;
  const int hd = w * 16 + c;
  const u8* wdir = wf8l + (long)dir * 768 * 256;

  long Breg[8][3];
#pragma unroll
  for (int kt = 0; kt < 8; ++kt)
#pragma unroll
    for (int g = 0; g < 3; ++g)
      Breg[kt][g] = *(const long*)(wdir + (long)(g * 256 + hd) * 256 + kt * 32 + q * 8);

  const float bias_n = bhhn_l[dir * 256 + hd];
  const int hbase = (layer * 2 + dir) * (16 * 256);

  for (int e = tid; e < 1056; e += 1024) ((u64*)hq)[e] = 0ull;
  __syncthreads();
  float hprev = h0[hbase + (bg * 4 + q) * 256 + hd];
  hq[0][q * 264 + hd] = f2e4m3(hprev);

  const int tt0 = dir ? 127 : 0;
  const long gstep = dir ? -24576 : 24576;
  const long ystep = dir ? -512 : 512;
  const u16* gp = gi4 + ((long)(tt0 * 2 + dir) * 4 + bg) * 3072 + q * 256 + hd;
  u16* yp = ybf + ((long)((bg * 4 + q) * 128) + tt0) * 512 + dir * 256 + hd;

  // 2-deep gate prefetch ring (manual 2x unroll alternates A/B, ~2 steps of slack)
  u16 gAr = gp[0], gAz = gp[1024], gAn = gp[2048];
  const u16* gp1 = gp + gstep;
  u16 gBr = gp1[0], gBz = gp1[1024], gBn = gp1[2048];
  const u16* gpp = gp + 2 * gstep;
  __syncthreads();

#pragma unroll 1
  for (int t = 0; t < 128; t += 2) {
    // ======== even step: reads hq[0], writes hq[1] ========
    {
      f32x4 a0 = {0.f, 0.f, 0.f, 0.f}, a1 = a0, a2 = a0;
#pragma unroll
      for (int kt = 0; kt < 8; ++kt) {
        long a = *(const long*)(hq[0] + c * 264 + kt * 32 + q * 8);
        a0 = __builtin_amdgcn_mfma_f32_16x16x32_fp8_fp8(a, Breg[kt][0], a0, 0, 0, 0);
        a1 = __builtin_amdgcn_mfma_f32_16x16x32_fp8_fp8(a, Breg[kt][1], a1, 0, 0, 0);
        a2 = __builtin_amdgcn_mfma_f32_16x16x32_fp8_fp8(a, Breg[kt][2], a2, 0, 0, 0);
      }
      if (q == 0) {
#pragma unroll
        for (int r = 0; r < 4; ++r) {
          accs[0][r][hd] = a0[r];
          accs[1][r][hd] = a1[r];
          accs[2][r][hd] = a2[r];
        }
      }
      // wave-local producer->consumer: drain LDS writes, no cross-wave barrier needed
      asm volatile("s_waitcnt lgkmcnt(0)" ::: "memory");
      float rg = sigm(bf2f(gAr) + accs[0][q][hd]);
      float zg = sigm(bf2f(gAz) + accs[1][q][hd]);
      float ng = tanh_s(bf2f(gAn) + rg * (accs[2][q][hd] + bias_n));
      float hv = (1.f - zg) * ng + zg * hprev;
      hprev = hv;
      yp[0] = f2bf(hv);
      hq[1][q * 264 + hd] =
          (u8)(__builtin_amdgcn_cvt_pk_fp8_f32(hv, hv, 0, false) & 0xff);
      if (t < 126) { gAr = gpp[0]; gAz = gpp[1024]; gAn = gpp[2048]; gpp += gstep; }
      yp += ystep;
      // lgkm-only barrier: publish hq[1] without draining global loads/stores
      asm volatile("s_waitcnt lgkmcnt(0)\n\ts_barrier" ::: "memory");
    }
    // ======== odd step: reads hq[1], writes hq[0] ========
    {
      f32x4 a0 = {0.f, 0.f, 0.f, 0.f}, a1 = a0, a2 = a0;
#pragma unroll
      for (int kt = 0; kt < 8; ++kt) {
        long a = *(const long*)(hq[1] + c * 264 + kt * 32 + q * 8);
        a0 = __builtin_amdgcn_mfma_f32_16x16x32_fp8_fp8(a, Breg[kt][0], a0, 0, 0, 0);
        a1 = __builtin_amdgcn_mfma_f32_16x16x32_fp8_fp8(a, Breg[kt][1], a1, 0, 0, 0);
        a2 = __builtin_amdgcn_mfma_f32_16x16x32_fp8_fp8(a, Breg[kt][2], a2, 0, 0, 0);
      }
      if (q == 0) {
#pragma unroll
        for (int r = 0; r < 4; ++r) {
          accs[0][r][hd] = a0[r];
          accs[1][r][hd] = a1[r];
          accs[2][r][hd] = a2[r];
        }
      }
      asm volatile("s_waitcnt lgkmcnt(0)" ::: "memory");
      float rg = sigm(bf2f(gBr) + accs[0][q][hd]);
      float zg = sigm(bf2f(gBz) + accs[1][q][hd]);
      float ng = tanh_s(bf2f(gBn) + rg * (accs[2][q][hd] + bias_n));
      float hv = (1.f - zg) * ng + zg * hprev;
      hprev = hv;
      yp[0] = f2bf(hv);
      hq[0][q * 264 + hd] =
          (u8)(__builtin_amdgcn_cvt_pk_fp8_f32(hv, hv, 0, false) & 0xff);
      if (t < 125) { gBr = gpp[0]; gBz = gpp[1024]; gBn = gpp[2048]; gpp += gstep; }
      yp += ystep;
      asm volatile("s_waitcnt lgkmcnt(0)\n\ts_barrier" ::: "memory");
    }
  }
  hn[hbase + (bg * 4 + q) * 256 + hd] = hprev;
}

// ---------------- attention softmax ----------------
__global__ void attn_kernel(const float* __restrict__ hn, const float* __restrict__ wlp,
                            const float* __restrict__ blp, const float* __restrict__ outsq,
                            float* __restrict__ attw) {
  int b = blockIdx.x, tid = threadIdx.x;
  __shared__ float hsq[256];
  __shared__ float sc[128];
  __shared__ float red[2];
  {
    float s = blp[0];
#pragma unroll
    for (int d = 0; d < 4; ++d) s += hn[d * 4096 + b * 256 + tid] * wlp[d];
    hsq[tid] = s;
  }
  __syncthreads();
  if (tid < 128) {
    float s = 0.f;
    const float* op = outsq + (long)(b * 128 + tid) * 256;
    for (int h = 0; h < 256; ++h) s += hsq[h] * op[h];
    sc[tid] = s;
  }
  __syncthreads();
  if (tid == 0) {
    float m = sc[0];
    for (int i = 1; i < 128; ++i) m = fmaxf(m, sc[i]);
    red[0] = m;
  }
  __syncthreads();
  if (tid < 128) sc[tid] = __expf(sc[tid] - red[0]);
  __syncthreads();
  if (tid == 0) {
    float s = 0.f;
    for (int i = 0; i < 128; ++i) s += sc[i];
    red[1] = s;
  }
  __syncthreads();
  if (tid < 128) attw[b * 128 + tid] = sc[tid] / red[1];
}

// ---------------- build rel_in (bf16, K padded to 576) ----------------
__global__ void build_relin(const u16* __restrict__ outbf, const int* __restrict__ tags,
                            const float* __restrict__ emb_tok, const float* __restrict__ attw,
                            u16* __restrict__ relin) {
  int i = blockIdx.x * 256 + threadIdx.x;
  if (i >= BL * 576) return;
  int bl = i / 576, cc = i % 576;
  u16 v;
  if (cc < 512) v = outbf[(long)bl * 512 + cc];
  else if (cc < 544) v = f2bf(emb_tok[tags[bl] * 32 + (cc - 512)]);
  else if (cc == 544) v = f2bf(attw[bl]);
  else v = 0;
  relin[i] = v;
}

// ---------------- ner scores [BL][10] ----------------
__global__ __launch_bounds__(256) void ner_kernel(
    const u16* __restrict__ outbf, const float* __restrict__ attw,
    const float* __restrict__ wner, const float* __restrict__ bner,
    float* __restrict__ ner) {
  __shared__ float wn[10 * 513];
  int tid = threadIdx.x;
  for (int e = tid; e < 5130; e += 256) wn[e] = wner[e];
  __syncthreads();
  int row0 = blockIdx.x * 64;
  for (int o = tid; o < 640; o += 256) {
    int rr = o / 10, t = o % 10;
    int row = row0 + rr;
    const u16* op = outbf + (long)row * 512;
    const float* wp = wn + t * 513;
    float s = bner[t] + attw[row] * wp[512];
    for (int k = 0; k < 512; ++k) s += bf2f(op[k]) * wp[k];
    ner[(long)row * 10 + t] = s;
  }
}

// ---------------- fused rel-branch BCE over 32x32 pair tiles ----------------
__global__ __launch_bounds__(512) void rel_kernel(
    const float* __restrict__ AC,    // [BL][256]: cols 0:128 = A(u-part, j), 128:256 = C(v-part, i)
    const int* __restrict__ gold,    // [16][128][128]
    const float* __restrict__ mask,  // [16][128]
    const float* __restrict__ embr,  // [24][128]
    float* __restrict__ acc_out) {
  __shared__ float Au[32 * 132];
  __shared__ float Cv[32 * 132];
  __shared__ float ER[24 * 128];
  __shared__ int GT[32 * 33];
  __shared__ float Mi[32], Mj[32];
  __shared__ float redbuf[8];
  int b = blockIdx.x, it = blockIdx.y, jt = blockIdx.z;
  int i0 = it * 32, j0 = jt * 32;
  int tid = threadIdx.x;
  for (int e = tid; e < 4096; e += 512) {
    int rr = e >> 7, h = e & 127;
    Au[rr * 132 + h] = AC[(long)(b * 128 + j0 + rr) * 256 + h];
    Cv[rr * 132 + h] = AC[(long)(b * 128 + i0 + rr) * 256 + 128 + h];
  }
  for (int e = tid; e < 3072; e += 512) ER[e] = embr[e];
  for (int e = tid; e < 1024; e += 512) {
    int ii = e >> 5, jj = e & 31;
    GT[ii * 33 + jj] = gold[(long)b * 16384 + (i0 + ii) * 128 + (j0 + jj)];
  }
  if (tid < 32) Mi[tid] = mask[b * 128 + i0 + tid];
  else if (tid < 64) Mj[tid - 32] = mask[b * 128 + j0 + tid - 32];
  __syncthreads();
  float sum = 0.f;
#pragma unroll 1
  for (int k = 0; k < 2; ++k) {
    int p = tid + k * 512;
    int ii = p >> 5, jj = p & 31;
    float pm = Mi[ii] * Mj[jj];
    int g = GT[ii * 33 + jj];
    float logits[24];
#pragma unroll
    for (int r = 0; r < 24; ++r) logits[r] = 0.f;
#pragma unroll 1
    for (int hc = 0; hc < 4; ++hc) {
      float tt[32];
#pragma unroll
      for (int x4 = 0; x4 < 8; ++x4) {
        float4 a4 = *(const float4*)(Au + jj * 132 + hc * 32 + x4 * 4);
        float4 c4 = *(const float4*)(Cv + ii * 132 + hc * 32 + x4 * 4);
        tt[x4 * 4 + 0] = tanh_s(a4.x + c4.x);
        tt[x4 * 4 + 1] = tanh_s(a4.y + c4.y);
        tt[x4 * 4 + 2] = tanh_s(a4.z + c4.z);
        tt[x4 * 4 + 3] = tanh_s(a4.w + c4.w);
      }
#pragma unroll
      for (int r = 0; r < 24; ++r) {
        float s = logits[r];
#pragma unroll
        for (int x4 = 0; x4 < 8; ++x4) {
          float4 e4 = *(const float4*)(ER + r * 128 + hc * 32 + x4 * 4);
          s += tt[x4 * 4] * e4.x + tt[x4 * 4 + 1] * e4.y +
               tt[x4 * 4 + 2] * e4.z + tt[x4 * 4 + 3] * e4.w;
        }
        logits[r] = s;
      }
    }
    float lsum = 0.f;
#pragma unroll
    for (int r = 0; r < 24; ++r) {
      float x = logits[r];
      float e = __expf(-fabsf(x));
      float l1p = __logf(1.f + e);
      float lsp = fminf(x, 0.f) - l1p;   // log_sigmoid(x)
      float lsn = fminf(-x, 0.f) - l1p;  // log_sigmoid(-x)
      float wr = r ? 50.f : 1.f;
      float pw = r ? 20.f : 1.f;
      lsum -= (r == g) ? (wr * pw * lsp) : (wr * lsn);
    }
    sum += lsum * pm;
  }
  for (int off = 32; off > 0; off >>= 1) sum += __shfl_down(sum, off, 64);
  if ((tid & 63) == 0) redbuf[tid >> 6] = sum;
  __syncthreads();
  if (tid == 0) {
    float s = 0.f;
    for (int x = 0; x < 8; ++x) s += redbuf[x];
    atomicAdd(acc_out, s);
  }
}

// ---------------- CRF log-likelihood (numerator + forward algo) ----------------
__global__ __launch_bounds__(512) void crf_kernel(
    const float* __restrict__ ner, const int* __restrict__ tags,
    const float* __restrict__ mask, const float* __restrict__ cs,
    const float* __restrict__ ct, const float* __restrict__ ce,
    float* __restrict__ scal) {
  __shared__ float tr[100];
  __shared__ float alpha[2][16][12];
  __shared__ float logZ[16], sc[16];
  __shared__ float red[8];
  int tid = threadIdx.x;
  if (tid < 100) tr[tid] = ct[tid];
  __syncthreads();
  int b = tid / 10, j = tid % 10;
  if (tid < 160) alpha[0][b][j] = cs[j] + ner[(long)(b * 128) * 10 + j];
  __syncthreads();
  int cur = 0;
  for (int t = 1; t < 128; ++t) {
    if (tid < 160) {
      float m = -1e30f;
#pragma unroll
      for (int i = 0; i < 10; ++i) m = fmaxf(m, alpha[cur][b][i] + tr[i * 10 + j]);
      float s = 0.f;
#pragma unroll
      for (int i = 0; i < 10; ++i) s += __expf(alpha[cur][b][i] + tr[i * 10 + j] - m);
      float v = m + __logf(s) + ner[(long)(b * 128 + t) * 10 + j];
      float mk = mask[b * 128 + t];
      alpha[1 - cur][b][j] = (mk > 0.f) ? v : alpha[cur][b][j];
    }
    __syncthreads();
    cur ^= 1;
  }
  if (tid < 16) {
    int bb = tid;
    float m = -1e30f;
    for (int jj = 0; jj < 10; ++jj) m = fmaxf(m, alpha[cur][bb][jj] + ce[jj]);
    float s = 0.f;
    for (int jj = 0; jj < 10; ++jj) s += __expf(alpha[cur][bb][jj] + ce[jj] - m);
    logZ[bb] = m + __logf(s);
    int tprev = tags[bb * 128];
    float sco = cs[tprev] + ner[(long)(bb * 128) * 10 + tprev];
    float msum_b = mask[bb * 128];
    for (int t = 1; t < 128; ++t) {
      int tc = tags[bb * 128 + t];
      float mk = mask[bb * 128 + t];
      sco += (tr[tprev * 10 + tc] + ner[(long)(bb * 128 + t) * 10 + tc]) * mk;
      msum_b += mk;
      tprev = tc;
    }
    int send = (int)(msum_b)-1;
    int last = tags[bb * 128 + send];
    sco += ce[last];
    sc[bb] = sco - logZ[bb];
  }
  float ms = 0.f;
  for (int e = tid; e < 2048; e += 512) ms += mask[e];
  for (int off = 32; off > 0; off >>= 1) ms += __shfl_down(ms, off, 64);
  if ((tid & 63) == 0) red[tid >> 6] = ms;
  __syncthreads();
  if (tid == 0) {
    float s = 0.f;
    for (int x = 0; x < 8; ++x) s += red[x];
    scal[1] = s;
    float llh = 0.f;
    for (int bb = 0; bb < 16; ++bb) llh += sc[bb];
    scal[0] = llh;
  }
}

__global__ void finalize_kernel(const float* __restrict__ scal, float* __restrict__ out) {
  if (threadIdx.x == 0 && blockIdx.x == 0) {
    out[0] = -scal[0];
    out[1] = scal[2] / scal[1];
  }
}

// ---------------- host launch ----------------
extern "C" void kernel_launch(void* const* d_in, const int* in_sizes, int n_in,
                              void* d_out, int out_size, void* d_ws, size_t ws_size,
                              hipStream_t stream) {
  (void)in_sizes; (void)n_in; (void)out_size; (void)ws_size;
  const int*   text = (const int*)d_in[0];
  const int*   tags = (const int*)d_in[1];
  const int*   gold = (const int*)d_in[2];
  const float* mask = (const float*)d_in[3];
  const float* h0   = (const float*)d_in[4];
  const float* embw = (const float*)d_in[5];
  const float* embt = (const float*)d_in[6];
  const float* embr = (const float*)d_in[7];
  const float* wih0 = (const float*)d_in[8];
  const float* whh0 = (const float*)d_in[9];
  const float* bih0 = (const float*)d_in[10];
  const float* bhh0 = (const float*)d_in[11];
  const float* wih1 = (const float*)d_in[12];
  const float* whh1 = (const float*)d_in[13];
  const float* bih1 = (const float*)d_in[14];
  const float* bhh1 = (const float*)d_in[15];
  const float* whp  = (const float*)d_in[16];
  const float* bhp  = (const float*)d_in[17];
  const float* wlp  = (const float*)d_in[18];
  const float* blp  = (const float*)d_in[19];
  const float* wner = (const float*)d_in[20];
  const float* bner = (const float*)d_in[21];
  const float* cs   = (const float*)d_in[22];
  const float* ct   = (const float*)d_in[23];
  const float* ce   = (const float*)d_in[24];
  const float* wu   = (const float*)d_in[25];
  const float* bu   = (const float*)d_in[26];
  const float* wv   = (const float*)d_in[27];
  const float* bv   = (const float*)d_in[28];
  const float* wuv  = (const float*)d_in[29];
  const float* buv  = (const float*)d_in[30];

  char* ws = (char*)d_ws;
  u16*   gi     = (u16*)(ws + 0);           // [128][2][4][3][4][256] bf16 (6.29 MB)
  u16*   xbf    = (u16*)(ws + 12582912);
  u16*   y0bf   = (u16*)(ws + 13631488);
  u8*    wf8    = (u8*)(ws + 15728640);     // [2][2][768][256] e4m3 (786432 B)
  float* bc     = (float*)(ws + 16515072);  // [2][1536] fused GEMM bias
  float* bhhn   = (float*)(ws + 16527360);  // [2][512] n-gate hh bias
  u16*   outbf  = (u16*)(ws + 19922944);
  float* hn     = (float*)(ws + 22020096);
  float* outsq  = (float*)(ws + 22085632);
  float* attw   = (float*)(ws + 24182784);
  u16*   relin  = (u16*)(ws + 24190976);
  u16*   uvbf   = (u16*)(ws + 28647424);
  float* ac32   = (float*)(ws + 29696000);
  float* ner    = (float*)(ws + 31793152);
  u16*   wih0b  = (u16*)(ws + 31875072);
  u16*   wih1b  = (u16*)(ws + 32661504);
  u16*   whpb   = (u16*)(ws + 34234368);
  u16*   wuvp   = (u16*)(ws + 34496512);
  u16*   wuvc   = (u16*)(ws + 34791424);
  float* buv2   = (float*)(ws + 34856960);
  float* scal   = (float*)(ws + 34859008);

  prep_kernel<<<8913, 256, 0, stream>>>(wih0, wih1, whp, wu, wv, wuv, bu, bv,
                                        whh0, whh1, bih0, bhh0, bih1, bhh1,
                                        wih0b, wih1b, whpb, wuvp, wuvc, buv2, scal,
                                        wf8, bc, bhhn);
  gather_x<<<2048, 256, 0, stream>>>(text, embw, xbf);
  gemm_bf16<<<dim3(32, 24), 256, 0, stream>>>(xbf, 256, wih0b, bc, nullptr, gi, 1536, 2048, 1536, 256, 1);
  gru_scan<<<dim3(2, 4), 1024, 0, stream>>>(gi, wf8, bhhn, h0, 0, hn, y0bf);
  gemm_bf16<<<dim3(32, 24), 256, 0, stream>>>(y0bf, 512, wih1b, bc + 1536, nullptr, gi, 1536, 2048, 1536, 512, 1);
  gru_scan<<<dim3(2, 4), 1024, 0, stream>>>(gi, wf8 + 393216, bhhn + 512, h0, 1, hn, outbf);
  gemm_bf16<<<dim3(32, 4), 256, 0, stream>>>(outbf, 512, whpb, bhp, outsq, nullptr, 256, 2048, 256, 512, 0);
  attn_kernel<<<16, 256, 0, stream>>>(hn, wlp, blp, outsq, attw);
  build_relin<<<4608, 256, 0, stream>>>(outbf, tags, embt, attw, relin);
  ner_kernel<<<32, 256, 0, stream>>>(outbf, attw, wner, bner, ner);
  gemm_bf16<<<dim3(32, 4), 256, 0, stream>>>(relin, 576, wuvp, buv2, nullptr, uvbf, 256, 2048, 256, 576, 0);
  // AC = [U @ wuv_u^T | V @ wuv_v^T + b_uv]
  gemm_bf16<<<dim3(32, 2), 256, 0, stream>>>(uvbf, 256, wuvc, nullptr, ac32, nullptr, 256, 2048, 128, 128, 0);
  gemm_bf16<<<dim3(32, 2), 256, 0, stream>>>(uvbf + 128, 256, wuvc + 128 * 128, buv, ac32 + 128, nullptr, 256, 2048, 128, 128, 0);
  rel_kernel<<<dim3(16, 4, 4), 512, 0, stream>>>(ac32, gold, mask, embr, scal + 2);
  crf_kernel<<<1, 512, 0, stream>>>(ner, tags, mask, cs, ct, ce, scal);
  finalize_kernel<<<1, 64, 0, stream>>>(scal, (float*)d_out);
}